// Round 1
// baseline (11463.081 us; speedup 1.0000x reference)
//
#include <hip/hip_runtime.h>
#include <hip/hip_bf16.h>
#include <math.h>

// DeepseekV2-Lite decoder layer, MI355X gfx950.
// Round 0: correctness-first. bf16 MFMA GEMMs (16x16x32, NT layout),
// VALU flash attention, fp32 residual spine.
//
// Shapes: B=2 S=2048 T=4096, H=16, D_NOPE=128 D_ROPE=64 D_Q=192 D_V=128,
// KV_RANK=512, HID=2048, INTER=10944.
//
// Workspace layout (total 229,638,144 B):
//   [0              , 16,777,216) xn  bf16 (T,2048)   -- reused as y after attn
//   [16,777,216     , +89,653,248) R1 region:
//        q bf16 (T,3072) | ckv f32 (T,576) | cn bf16 (T,512) |
//        kv bf16 (T,4096) | kpe bf16 (T,64) | attno bf16 (T,2048)
//        -- entire region later aliased by g bf16 (T,10944) (sizes match exactly)
//   [106,430,464    , +89,653,248) u bf16 (T,10944)
//   [196,083,712    , +33,554,432) h1 f32 (T,2048)

typedef short short8 __attribute__((ext_vector_type(8)));
typedef float f32x4 __attribute__((ext_vector_type(4)));

static __device__ __forceinline__ float bf2f(ushort u) {
  union { uint i; float f; } v; v.i = ((uint)u) << 16; return v.f;
}
static __device__ __forceinline__ ushort f2bf(float x) {
  union { float f; uint i; } v; v.f = x;
  uint r = v.i + 0x7fffu + ((v.i >> 16) & 1u);
  return (ushort)(r >> 16);
}

// ---------------- RMSNorm (fp32 in -> bf16 out) ----------------
__global__ __launch_bounds__(256)
void rms_bf16(const float* __restrict__ in, int istride, int width, float inv_w,
              const float* __restrict__ w, ushort* __restrict__ out, int ostride) {
  const int row = blockIdx.x;
  const float* x = in + (size_t)row * istride;
  float ss = 0.f;
  for (int i = threadIdx.x; i < width; i += 256) { float v = x[i]; ss += v * v; }
#pragma unroll
  for (int off = 32; off > 0; off >>= 1) ss += __shfl_xor(ss, off);
  __shared__ float red[4];
  if ((threadIdx.x & 63) == 0) red[threadIdx.x >> 6] = ss;
  __syncthreads();
  float tot = red[0] + red[1] + red[2] + red[3];
  float scale = rsqrtf(tot * inv_w + 1e-6f);
  ushort* o = out + (size_t)row * ostride;
  for (int i = threadIdx.x; i < width; i += 256) o[i] = f2bf(x[i] * scale * w[i]);
}

// ---------------- GEMM: C[M,N] = A[M,K](bf16) @ W[N,K]^T(f32) ----------------
// EPI 0: C bf16; EPI 1: C f32; EPI 2: C f32 = res + acc
// Requires M%128==0, K%32==0. N arbitrary (guarded).
template<int EPI>
__global__ __launch_bounds__(256, 2)
void gemm_nt(const ushort* __restrict__ A, const float* __restrict__ W,
             void* __restrict__ Cv, const float* __restrict__ res,
             int M, int N, int K) {
  __shared__ __align__(16) ushort As[128][40];
  __shared__ __align__(16) ushort Bs[128][40];
  const int tid = threadIdx.x;
  const int m0 = blockIdx.x * 128;
  const int n0 = blockIdx.y * 128;
  const int wave = tid >> 6;
  const int lane = tid & 63;
  const int wm = (wave & 1) * 64;
  const int wn = (wave >> 1) * 64;
  const int lm = lane & 15;
  const int quad = lane >> 4;

  f32x4 acc[4][4];
  const f32x4 z4 = {0.f, 0.f, 0.f, 0.f};
#pragma unroll
  for (int i = 0; i < 4; ++i)
#pragma unroll
    for (int j = 0; j < 4; ++j) acc[i][j] = z4;

  const int sr = tid >> 2;        // 0..63
  const int sc = (tid & 3) * 8;   // 0,8,16,24
  const ushort* a0 = A + (size_t)(m0 + sr) * K + sc;
  const ushort* a1 = A + (size_t)(m0 + sr + 64) * K + sc;
  const int bn0 = n0 + sr, bn1 = n0 + sr + 64;
  const float* w0 = W + (size_t)bn0 * K + sc;
  const float* w1 = W + (size_t)bn1 * K + sc;
  const bool v0 = bn0 < N, v1 = bn1 < N;
  const float4 fz = {0.f, 0.f, 0.f, 0.f};

  for (int k0 = 0; k0 < K; k0 += 32) {
    uint4 av0 = *(const uint4*)(a0 + k0);
    uint4 av1 = *(const uint4*)(a1 + k0);
    float4 b0a = v0 ? *(const float4*)(w0 + k0)     : fz;
    float4 b0b = v0 ? *(const float4*)(w0 + k0 + 4) : fz;
    float4 b1a = v1 ? *(const float4*)(w1 + k0)     : fz;
    float4 b1b = v1 ? *(const float4*)(w1 + k0 + 4) : fz;
    __syncthreads();
    *(uint4*)&As[sr][sc]      = av0;
    *(uint4*)&As[sr + 64][sc] = av1;
    short8 bs0, bs1;
    bs0[0] = (short)f2bf(b0a.x); bs0[1] = (short)f2bf(b0a.y);
    bs0[2] = (short)f2bf(b0a.z); bs0[3] = (short)f2bf(b0a.w);
    bs0[4] = (short)f2bf(b0b.x); bs0[5] = (short)f2bf(b0b.y);
    bs0[6] = (short)f2bf(b0b.z); bs0[7] = (short)f2bf(b0b.w);
    bs1[0] = (short)f2bf(b1a.x); bs1[1] = (short)f2bf(b1a.y);
    bs1[2] = (short)f2bf(b1a.z); bs1[3] = (short)f2bf(b1a.w);
    bs1[4] = (short)f2bf(b1b.x); bs1[5] = (short)f2bf(b1b.y);
    bs1[6] = (short)f2bf(b1b.z); bs1[7] = (short)f2bf(b1b.w);
    *(short8*)&Bs[sr][sc]      = bs0;
    *(short8*)&Bs[sr + 64][sc] = bs1;
    __syncthreads();

    short8 afr[4], bfr[4];
#pragma unroll
    for (int mt = 0; mt < 4; ++mt)
      afr[mt] = *(const short8*)&As[wm + mt * 16 + lm][quad * 8];
#pragma unroll
    for (int nt = 0; nt < 4; ++nt)
      bfr[nt] = *(const short8*)&Bs[wn + nt * 16 + lm][quad * 8];
#pragma unroll
    for (int mt = 0; mt < 4; ++mt)
#pragma unroll
      for (int nt = 0; nt < 4; ++nt)
        acc[mt][nt] = __builtin_amdgcn_mfma_f32_16x16x32_bf16(
            afr[mt], bfr[nt], acc[mt][nt], 0, 0, 0);
  }

  // C/D layout: col = lane&15, row = quad*4 + reg   [m89-verified]
#pragma unroll
  for (int mt = 0; mt < 4; ++mt) {
#pragma unroll
    for (int r = 0; r < 4; ++r) {
      const int grow = m0 + wm + mt * 16 + quad * 4 + r;
#pragma unroll
      for (int nt = 0; nt < 4; ++nt) {
        const int gcol = n0 + wn + nt * 16 + lm;
        if (gcol < N) {
          float vacc = acc[mt][nt][r];
          if (EPI == 0)
            ((ushort*)Cv)[(size_t)grow * N + gcol] = f2bf(vacc);
          else if (EPI == 1)
            ((float*)Cv)[(size_t)grow * N + gcol] = vacc;
          else
            ((float*)Cv)[(size_t)grow * N + gcol] =
                vacc + res[(size_t)grow * N + gcol];
        }
      }
    }
  }
}

// ---------------- YaRN RoPE: q_pe in place (bf16), k_pe ckv->bf16 ----------------
__global__ __launch_bounds__(64)
void rope_kernel(ushort* __restrict__ q, const float* __restrict__ ckv,
                 const int* __restrict__ pos_ids, ushort* __restrict__ kpe) {
  const int t = blockIdx.x;
  const int j = threadIdx.x;        // 0..63 output dim
  const int j2 = j & 31;            // frequency index
  const float ar = (float)j2 * (1.f / 32.f);
  const float fe = exp2f(-ar * 13.287712379549449f);  // 10000^-ar
  const float fi = fe * 0.025f;                       // /40
  float ramp = ((float)j2 - 10.f) * (1.f / 13.f);     // low=10, high=23
  ramp = fminf(fmaxf(ramp, 0.f), 1.f);
  const float invf = fi * ramp + fe * (1.f - ramp);   // mscale ratio = 1.0
  const float ang = (float)pos_ids[t] * invf;
  const float c = cosf(ang), s = sinf(ang);
  const bool lo = j < 32;
  // k_pe from ckv cols [512,576)
  {
    const float* kp = ckv + (size_t)t * 576 + 512;
    float x0 = kp[2 * j2], x1 = kp[2 * j2 + 1];
    float o = lo ? (x0 * c - x1 * s) : (x1 * c + x0 * s);
    kpe[(size_t)t * 64 + j] = f2bf(o);
  }
  // q_pe (cols [128,192) of each head), in place. Single wave: loads of the
  // pair complete (feed 'o') before the store instruction issues.
  for (int h = 0; h < 16; ++h) {
    ushort* qp = q + (size_t)t * 3072 + h * 192 + 128;
    float x0 = bf2f(qp[2 * j2]), x1 = bf2f(qp[2 * j2 + 1]);
    float o = lo ? (x0 * c - x1 * s) : (x1 * c + x0 * s);
    __syncthreads();
    qp[j] = f2bf(o);
  }
}

// ---------------- Attention: one wave per (token, head) ----------------
// q: (T,16,192) bf16 roped; kv: (T,16,256) bf16 [k_nope|v]; kpe: (T,64) bf16
// out: (T, 16*128) bf16
__global__ __launch_bounds__(64)
void attn_kernel(const ushort* __restrict__ q, const ushort* __restrict__ kv,
                 const ushort* __restrict__ kpe, ushort* __restrict__ out) {
  __shared__ float Qs[192];
  __shared__ float plds[2048];
  const int t = blockIdx.x;
  const int h = blockIdx.y;
  const int lane = threadIdx.x;
  const int b = t >> 11;
  const int qp = t & 2047;
  const int nk = qp + 1;
  const size_t tok0 = (size_t)b << 11;
  const float scale = 0.07216878364870323f;  // 192^-0.5

  const ushort* qrow = q + (size_t)t * 3072 + h * 192;
  for (int i = lane; i < 192; i += 64) Qs[i] = bf2f(qrow[i]) * scale;
  __syncthreads();

  // pass 1: scores -> plds, track max
  float mx = -3.0e38f;
  for (int kk = lane; kk < nk; kk += 64) {
    const ushort* krow = kv + (((tok0 + kk) * 16 + h) << 8);
    float s = 0.f;
#pragma unroll
    for (int c = 0; c < 128; c += 8) {
      short8 k8 = *(const short8*)(krow + c);
#pragma unroll
      for (int jj = 0; jj < 8; ++jj) s += Qs[c + jj] * bf2f((ushort)k8[jj]);
    }
    const ushort* prow = kpe + ((tok0 + kk) << 6);
#pragma unroll
    for (int c = 0; c < 64; c += 8) {
      short8 k8 = *(const short8*)(prow + c);
#pragma unroll
      for (int jj = 0; jj < 8; ++jj) s += Qs[128 + c + jj] * bf2f((ushort)k8[jj]);
    }
    plds[kk] = s;
    mx = fmaxf(mx, s);
  }
#pragma unroll
  for (int off = 32; off > 0; off >>= 1) mx = fmaxf(mx, __shfl_xor(mx, off));

  // pass 2: exp + sum
  float sum = 0.f;
  for (int kk = lane; kk < nk; kk += 64) {
    float p = expf(plds[kk] - mx);
    plds[kk] = p;
    sum += p;
  }
#pragma unroll
  for (int off = 32; off > 0; off >>= 1) sum += __shfl_xor(sum, off);
  __syncthreads();

  // pass 3: O[d] = sum_k p_k * V[k][d]; lane owns dims {2l, 2l+1}
  float o0 = 0.f, o1 = 0.f;
  const ushort* vbase = kv + ((tok0 * 16 + h) << 8) + 128 + 2 * lane;
  for (int kk = 0; kk < nk; ++kk) {
    float p = plds[kk];
    uint vv = *(const uint*)(vbase + (size_t)kk * 4096);
    o0 += p * bf2f((ushort)(vv & 0xffffu));
    o1 += p * bf2f((ushort)(vv >> 16));
  }
  const float inv = 1.f / sum;
  ushort2 ov;
  ov.x = f2bf(o0 * inv);
  ov.y = f2bf(o1 * inv);
  *(ushort2*)(out + (size_t)t * 2048 + h * 128 + 2 * lane) = ov;
}

// ---------------- act = silu(g) * u (bf16, in place into g) ----------------
__global__ __launch_bounds__(256)
void silu_mul(ushort* __restrict__ g, const ushort* __restrict__ u, size_t n8) {
  size_t i = (size_t)blockIdx.x * 256 + threadIdx.x;
  if (i >= n8) return;
  short8 gs = ((const short8*)g)[i];
  short8 us = ((const short8*)u)[i];
  short8 os;
#pragma unroll
  for (int j = 0; j < 8; ++j) {
    float gf = bf2f((ushort)gs[j]);
    float uf = bf2f((ushort)us[j]);
    float a = gf / (1.f + expf(-gf)) * uf;
    os[j] = (short)f2bf(a);
  }
  ((short8*)g)[i] = os;
}

extern "C" void kernel_launch(void* const* d_in, const int* in_sizes, int n_in,
                              void* d_out, int out_size, void* d_ws, size_t ws_size,
                              hipStream_t stream) {
  const float* hidden = (const float*)d_in[0];
  const int*   pos    = (const int*)d_in[1];
  const float* Wq     = (const float*)d_in[2];
  const float* Wkva   = (const float*)d_in[3];
  const float* w_kvln = (const float*)d_in[4];
  const float* Wkvb   = (const float*)d_in[5];
  const float* Wo     = (const float*)d_in[6];
  const float* Wg     = (const float*)d_in[7];
  const float* Wu     = (const float*)d_in[8];
  const float* Wd     = (const float*)d_in[9];
  const float* w_ln1  = (const float*)d_in[10];
  const float* w_ln2  = (const float*)d_in[11];
  float* out = (float*)d_out;

  char* ws = (char*)d_ws;
  ushort* xn    = (ushort*)(ws);                       // (T,2048) bf16; also y
  char*   R1    = ws + 16777216;
  ushort* qb    = (ushort*)(R1);                       // (T,3072) bf16
  float*  ckv   = (float*)(R1 + 25165824);             // (T,576)  f32
  ushort* cn    = (ushort*)(R1 + 34603008);            // (T,512)  bf16
  ushort* kvb   = (ushort*)(R1 + 38797312);            // (T,4096) bf16
  ushort* kpe   = (ushort*)(R1 + 72351744);            // (T,64)   bf16
  ushort* attno = (ushort*)(R1 + 72876032);            // (T,2048) bf16
  ushort* gb    = (ushort*)(R1);                       // (T,10944) bf16 aliases R1
  ushort* ub    = (ushort*)(ws + 106430464);           // (T,10944) bf16
  float*  h1    = (float*)(ws + 196083712);            // (T,2048) f32

  // 1. ln1
  rms_bf16<<<4096, 256, 0, stream>>>(hidden, 2048, 2048, 1.f / 2048.f, w_ln1, xn, 2048);
  // 2. q = xn @ Wq^T
  gemm_nt<0><<<dim3(32, 24), 256, 0, stream>>>(xn, Wq, qb, nullptr, 4096, 3072, 2048);
  // 3. ckv = xn @ Wkva^T (f32)
  gemm_nt<1><<<dim3(32, 5), 256, 0, stream>>>(xn, Wkva, ckv, nullptr, 4096, 576, 2048);
  // 4. cn = rms(ckv[:, :512]) * w_kvln
  rms_bf16<<<4096, 256, 0, stream>>>(ckv, 576, 512, 1.f / 512.f, w_kvln, cn, 512);
  // 5. kv = cn @ Wkvb^T
  gemm_nt<0><<<dim3(32, 32), 256, 0, stream>>>(cn, Wkvb, kvb, nullptr, 4096, 4096, 512);
  // 6. RoPE (q_pe in place; k_pe -> kpe)
  rope_kernel<<<4096, 64, 0, stream>>>(qb, ckv, pos, kpe);
  // 7. attention
  attn_kernel<<<dim3(4096, 16), 64, 0, stream>>>(qb, kvb, kpe, attno);
  // 8. h1 = hidden + attno @ Wo^T
  gemm_nt<2><<<dim3(32, 16), 256, 0, stream>>>(attno, Wo, h1, hidden, 4096, 2048, 2048);
  // 9. y = rms(h1) * w_ln2  (into xn)
  rms_bf16<<<4096, 256, 0, stream>>>(h1, 2048, 2048, 1.f / 2048.f, w_ln2, xn, 2048);
  // 10/11. gate & up
  gemm_nt<0><<<dim3(32, 86), 256, 0, stream>>>(xn, Wg, gb, nullptr, 4096, 10944, 2048);
  gemm_nt<0><<<dim3(32, 86), 256, 0, stream>>>(xn, Wu, ub, nullptr, 4096, 10944, 2048);
  // 12. act = silu(g) * u (in place into g)
  silu_mul<<<21888, 256, 0, stream>>>(gb, ub, (size_t)4096 * 10944 / 8);
  // 13. out = h1 + act @ Wd^T
  gemm_nt<2><<<dim3(32, 16), 256, 0, stream>>>(gb, Wd, out, h1, 4096, 2048, 10944);
}

// Round 2
// 5509.266 us; speedup vs baseline: 2.0807x; 2.0807x over previous
//
#include <hip/hip_runtime.h>
#include <hip/hip_bf16.h>
#include <math.h>

// DeepseekV2-Lite decoder layer, MI355X gfx950.
// Round 1: flash-style MFMA attention (replaces VALU attention).
// GEMMs unchanged from round 0 (next round: bf16 weight pre-convert + global_load_lds).
//
// Shapes: B=2 S=2048 T=4096, H=16, D_NOPE=128 D_ROPE=64 D_Q=192 D_V=128,
// KV_RANK=512, HID=2048, INTER=10944.

typedef short short8 __attribute__((ext_vector_type(8)));
typedef short short4v __attribute__((ext_vector_type(4)));
typedef float f32x4 __attribute__((ext_vector_type(4)));

static __device__ __forceinline__ float bf2f(ushort u) {
  union { uint i; float f; } v; v.i = ((uint)u) << 16; return v.f;
}
static __device__ __forceinline__ ushort f2bf(float x) {
  union { float f; uint i; } v; v.f = x;
  uint r = v.i + 0x7fffu + ((v.i >> 16) & 1u);
  return (ushort)(r >> 16);
}

// ---------------- RMSNorm (fp32 in -> bf16 out) ----------------
__global__ __launch_bounds__(256)
void rms_bf16(const float* __restrict__ in, int istride, int width, float inv_w,
              const float* __restrict__ w, ushort* __restrict__ out, int ostride) {
  const int row = blockIdx.x;
  const float* x = in + (size_t)row * istride;
  float ss = 0.f;
  for (int i = threadIdx.x; i < width; i += 256) { float v = x[i]; ss += v * v; }
#pragma unroll
  for (int off = 32; off > 0; off >>= 1) ss += __shfl_xor(ss, off);
  __shared__ float red[4];
  if ((threadIdx.x & 63) == 0) red[threadIdx.x >> 6] = ss;
  __syncthreads();
  float tot = red[0] + red[1] + red[2] + red[3];
  float scale = rsqrtf(tot * inv_w + 1e-6f);
  ushort* o = out + (size_t)row * ostride;
  for (int i = threadIdx.x; i < width; i += 256) o[i] = f2bf(x[i] * scale * w[i]);
}

// ---------------- GEMM: C[M,N] = A[M,K](bf16) @ W[N,K]^T(f32) ----------------
// EPI 0: C bf16; EPI 1: C f32; EPI 2: C f32 = res + acc
template<int EPI>
__global__ __launch_bounds__(256, 2)
void gemm_nt(const ushort* __restrict__ A, const float* __restrict__ W,
             void* __restrict__ Cv, const float* __restrict__ res,
             int M, int N, int K) {
  __shared__ __align__(16) ushort As[128][40];
  __shared__ __align__(16) ushort Bs[128][40];
  const int tid = threadIdx.x;
  const int m0 = blockIdx.x * 128;
  const int n0 = blockIdx.y * 128;
  const int wave = tid >> 6;
  const int lane = tid & 63;
  const int wm = (wave & 1) * 64;
  const int wn = (wave >> 1) * 64;
  const int lm = lane & 15;
  const int quad = lane >> 4;

  f32x4 acc[4][4];
  const f32x4 z4 = {0.f, 0.f, 0.f, 0.f};
#pragma unroll
  for (int i = 0; i < 4; ++i)
#pragma unroll
    for (int j = 0; j < 4; ++j) acc[i][j] = z4;

  const int sr = tid >> 2;
  const int sc = (tid & 3) * 8;
  const ushort* a0 = A + (size_t)(m0 + sr) * K + sc;
  const ushort* a1 = A + (size_t)(m0 + sr + 64) * K + sc;
  const int bn0 = n0 + sr, bn1 = n0 + sr + 64;
  const float* w0 = W + (size_t)bn0 * K + sc;
  const float* w1 = W + (size_t)bn1 * K + sc;
  const bool v0 = bn0 < N, v1 = bn1 < N;
  const float4 fz = {0.f, 0.f, 0.f, 0.f};

  for (int k0 = 0; k0 < K; k0 += 32) {
    uint4 av0 = *(const uint4*)(a0 + k0);
    uint4 av1 = *(const uint4*)(a1 + k0);
    float4 b0a = v0 ? *(const float4*)(w0 + k0)     : fz;
    float4 b0b = v0 ? *(const float4*)(w0 + k0 + 4) : fz;
    float4 b1a = v1 ? *(const float4*)(w1 + k0)     : fz;
    float4 b1b = v1 ? *(const float4*)(w1 + k0 + 4) : fz;
    __syncthreads();
    *(uint4*)&As[sr][sc]      = av0;
    *(uint4*)&As[sr + 64][sc] = av1;
    short8 bs0, bs1;
    bs0[0] = (short)f2bf(b0a.x); bs0[1] = (short)f2bf(b0a.y);
    bs0[2] = (short)f2bf(b0a.z); bs0[3] = (short)f2bf(b0a.w);
    bs0[4] = (short)f2bf(b0b.x); bs0[5] = (short)f2bf(b0b.y);
    bs0[6] = (short)f2bf(b0b.z); bs0[7] = (short)f2bf(b0b.w);
    bs1[0] = (short)f2bf(b1a.x); bs1[1] = (short)f2bf(b1a.y);
    bs1[2] = (short)f2bf(b1a.z); bs1[3] = (short)f2bf(b1a.w);
    bs1[4] = (short)f2bf(b1b.x); bs1[5] = (short)f2bf(b1b.y);
    bs1[6] = (short)f2bf(b1b.z); bs1[7] = (short)f2bf(b1b.w);
    *(short8*)&Bs[sr][sc]      = bs0;
    *(short8*)&Bs[sr + 64][sc] = bs1;
    __syncthreads();

    short8 afr[4], bfr[4];
#pragma unroll
    for (int mt = 0; mt < 4; ++mt)
      afr[mt] = *(const short8*)&As[wm + mt * 16 + lm][quad * 8];
#pragma unroll
    for (int nt = 0; nt < 4; ++nt)
      bfr[nt] = *(const short8*)&Bs[wn + nt * 16 + lm][quad * 8];
#pragma unroll
    for (int mt = 0; mt < 4; ++mt)
#pragma unroll
      for (int nt = 0; nt < 4; ++nt)
        acc[mt][nt] = __builtin_amdgcn_mfma_f32_16x16x32_bf16(
            afr[mt], bfr[nt], acc[mt][nt], 0, 0, 0);
  }

#pragma unroll
  for (int mt = 0; mt < 4; ++mt) {
#pragma unroll
    for (int r = 0; r < 4; ++r) {
      const int grow = m0 + wm + mt * 16 + quad * 4 + r;
#pragma unroll
      for (int nt = 0; nt < 4; ++nt) {
        const int gcol = n0 + wn + nt * 16 + lm;
        if (gcol < N) {
          float vacc = acc[mt][nt][r];
          if (EPI == 0)
            ((ushort*)Cv)[(size_t)grow * N + gcol] = f2bf(vacc);
          else if (EPI == 1)
            ((float*)Cv)[(size_t)grow * N + gcol] = vacc;
          else
            ((float*)Cv)[(size_t)grow * N + gcol] =
                vacc + res[(size_t)grow * N + gcol];
        }
      }
    }
  }
}

// ---------------- YaRN RoPE ----------------
__global__ __launch_bounds__(64)
void rope_kernel(ushort* __restrict__ q, const float* __restrict__ ckv,
                 const int* __restrict__ pos_ids, ushort* __restrict__ kpe) {
  const int t = blockIdx.x;
  const int j = threadIdx.x;
  const int j2 = j & 31;
  const float ar = (float)j2 * (1.f / 32.f);
  const float fe = exp2f(-ar * 13.287712379549449f);
  const float fi = fe * 0.025f;
  float ramp = ((float)j2 - 10.f) * (1.f / 13.f);
  ramp = fminf(fmaxf(ramp, 0.f), 1.f);
  const float invf = fi * ramp + fe * (1.f - ramp);
  const float ang = (float)pos_ids[t] * invf;
  const float c = cosf(ang), s = sinf(ang);
  const bool lo = j < 32;
  {
    const float* kp = ckv + (size_t)t * 576 + 512;
    float x0 = kp[2 * j2], x1 = kp[2 * j2 + 1];
    float o = lo ? (x0 * c - x1 * s) : (x1 * c + x0 * s);
    kpe[(size_t)t * 64 + j] = f2bf(o);
  }
  for (int h = 0; h < 16; ++h) {
    ushort* qp = q + (size_t)t * 3072 + h * 192 + 128;
    float x0 = bf2f(qp[2 * j2]), x1 = bf2f(qp[2 * j2 + 1]);
    float o = lo ? (x0 * c - x1 * s) : (x1 * c + x0 * s);
    __syncthreads();
    qp[j] = f2bf(o);
  }
}

// ---------------- Flash MFMA attention ----------------
// grid: (16 q-tiles, B*H=32); block 256 (4 waves x 32 q-rows).
// q: (T,16,192) bf16 roped; kv: (T,16,256) bf16 [k_nope|v]; kpe: (T,64) bf16
// out: (T, 16*128) bf16
__global__ __launch_bounds__(256, 2)
void attn_mfma(const ushort* __restrict__ q, const ushort* __restrict__ kv,
               const ushort* __restrict__ kpe, ushort* __restrict__ out) {
  const int qt = (int)gridDim.x - 1 - (int)blockIdx.x;  // heavy tiles first
  const int bh = blockIdx.y;
  const int b = bh >> 4, h = bh & 15;
  const int tid = threadIdx.x;
  const int wave = tid >> 6, lane = tid & 63;
  const int lm = lane & 15, quad = lane >> 4;
  const int wq = wave * 32;
  const float scale = 0.07216878364870323f;  // 192^-0.5

  // LDS: Ks 64x200 (25600B) | Vt 128x72 (18432B) | Pm 128x72 (18432B) = 62464B
  __shared__ __align__(16) char smem[62464];
  ushort (*Ks)[200] = (ushort(*)[200])smem;           // [key][0..191] = k_nope|kpe
  ushort (*Vt)[72]  = (ushort(*)[72])(smem + 25600);  // [dim][key]
  ushort (*Pm)[72]  = (ushort(*)[72])(smem + 44032);  // [q][key]
  ushort (*Qs)[200] = (ushort(*)[200])smem;           // staging alias

  const size_t tok0 = (size_t)b * 2048;
  const int q0 = qt * 128;

  // ---- stage Q tile (128 x 192) and pull A-fragments into registers ----
  {
    const ushort* qbase = q + (tok0 + q0) * 3072 + (size_t)h * 192;
#pragma unroll
    for (int it = 0; it < 12; ++it) {
      int idx = (it * 256 + tid) * 8;
      int row = idx / 192, col = idx % 192;
      *(uint4*)&Qs[row][col] = *(const uint4*)(qbase + (size_t)row * 3072 + col);
    }
  }
  __syncthreads();
  short8 qf[2][6];
#pragma unroll
  for (int mt = 0; mt < 2; ++mt)
#pragma unroll
    for (int kk = 0; kk < 6; ++kk)
      qf[mt][kk] = *(const short8*)&Qs[wq + mt * 16 + lm][kk * 32 + quad * 8];
  __syncthreads();  // Qs reads done before Ks staging overwrites

  f32x4 o[2][8];
  const f32x4 z4 = {0.f, 0.f, 0.f, 0.f};
#pragma unroll
  for (int mt = 0; mt < 2; ++mt)
#pragma unroll
    for (int nt = 0; nt < 8; ++nt) o[mt][nt] = z4;
  float m_run[8], l_run[8];
#pragma unroll
  for (int i = 0; i < 8; ++i) { m_run[i] = -3.0e38f; l_run[i] = 0.f; }

  const int nkt = 2 * qt + 2;
  for (int kt = 0; kt < nkt; ++kt) {
    const int kb = kt * 64;

    // ---- stage K (k_nope + kpe) and V^T ----
    {
      // k_nope: 64 keys x 128 shorts; thread: key=tid>>2, quarter covers 64B
      const int krow = tid >> 2, kq = tid & 3;
      const ushort* src = kv + ((tok0 + kb + krow) * 16 + h) * 256 + kq * 32;
#pragma unroll
      for (int i = 0; i < 4; ++i)
        *(uint4*)&Ks[krow][kq * 32 + i * 8] = *(const uint4*)(src + i * 8);
      // kpe: 64 keys x 64 shorts -> Ks[key][128..191]
      const ushort* psrc = kpe + (tok0 + kb + krow) * 64 + kq * 16;
      *(uint4*)&Ks[krow][128 + kq * 16]     = *(const uint4*)(psrc);
      *(uint4*)&Ks[krow][128 + kq * 16 + 8] = *(const uint4*)(psrc + 8);
      // V^T: thread handles keys (tid&15)*4..+3, dims (tid>>4)*8..+7
      const int kgrp = (tid & 15) * 4, dgrp = (tid >> 4) * 8;
      uint4 vv[4];
#pragma unroll
      for (int i = 0; i < 4; ++i)
        vv[i] = *(const uint4*)(kv + ((tok0 + kb + kgrp + i) * 16 + h) * 256 + 128 + dgrp);
#pragma unroll
      for (int j = 0; j < 8; ++j) {
        short4v w;
#pragma unroll
        for (int i = 0; i < 4; ++i) w[i] = (short)((const ushort*)&vv[i])[j];
        *(short4v*)&Vt[dgrp + j][kgrp] = w;
      }
    }
    __syncthreads();

    // ---- S = Q @ K^T  (per wave: 32 q-rows x 64 keys) ----
    f32x4 s_acc[2][4];
#pragma unroll
    for (int mt = 0; mt < 2; ++mt)
#pragma unroll
      for (int nt = 0; nt < 4; ++nt) s_acc[mt][nt] = z4;
#pragma unroll
    for (int kk = 0; kk < 6; ++kk) {
      short8 kf[4];
#pragma unroll
      for (int nt = 0; nt < 4; ++nt)
        kf[nt] = *(const short8*)&Ks[nt * 16 + lm][kk * 32 + quad * 8];
#pragma unroll
      for (int mt = 0; mt < 2; ++mt)
#pragma unroll
        for (int nt = 0; nt < 4; ++nt)
          s_acc[mt][nt] = __builtin_amdgcn_mfma_f32_16x16x32_bf16(
              qf[mt][kk], kf[nt], s_acc[mt][nt], 0, 0, 0);
    }

    // ---- online softmax + P write (C-layout: row=quad*4+r, col=lane&15) ----
#pragma unroll
    for (int mt = 0; mt < 2; ++mt) {
#pragma unroll
      for (int r = 0; r < 4; ++r) {
        const int qg = q0 + wq + mt * 16 + quad * 4 + r;
        float sv[4];
        float rm = -3.0e38f;
#pragma unroll
        for (int nt = 0; nt < 4; ++nt) {
          const int key = kb + nt * 16 + lm;
          float s = s_acc[mt][nt][r] * scale;
          s = (key <= qg) ? s : -3.0e38f;
          sv[nt] = s;
          rm = fmaxf(rm, s);
        }
#pragma unroll
        for (int off = 1; off < 16; off <<= 1) rm = fmaxf(rm, __shfl_xor(rm, off));
        const int li = mt * 4 + r;
        const float mnew = fmaxf(m_run[li], rm);
        const float alpha = expf(m_run[li] - mnew);
        m_run[li] = mnew;
        float rs = 0.f;
        ushort pb[4];
#pragma unroll
        for (int nt = 0; nt < 4; ++nt) {
          float p = expf(sv[nt] - mnew);
          rs += p;
          pb[nt] = f2bf(p);
        }
#pragma unroll
        for (int off = 1; off < 16; off <<= 1) rs += __shfl_xor(rs, off);
        l_run[li] = l_run[li] * alpha + rs;
#pragma unroll
        for (int nt = 0; nt < 8; ++nt) o[mt][nt][r] *= alpha;
        const int qrow = wq + mt * 16 + quad * 4 + r;
#pragma unroll
        for (int nt = 0; nt < 4; ++nt) Pm[qrow][nt * 16 + lm] = pb[nt];
      }
    }

    // ---- O += P @ V  (A = P[q][key], B = Vt[dim][key]) ----
#pragma unroll
    for (int kt2 = 0; kt2 < 2; ++kt2) {
      short8 pa[2];
#pragma unroll
      for (int mt = 0; mt < 2; ++mt)
        pa[mt] = *(const short8*)&Pm[wq + mt * 16 + lm][kt2 * 32 + quad * 8];
#pragma unroll
      for (int nt = 0; nt < 8; ++nt) {
        short8 vb = *(const short8*)&Vt[nt * 16 + lm][kt2 * 32 + quad * 8];
#pragma unroll
        for (int mt = 0; mt < 2; ++mt)
          o[mt][nt] = __builtin_amdgcn_mfma_f32_16x16x32_bf16(
              pa[mt], vb, o[mt][nt], 0, 0, 0);
      }
    }
    __syncthreads();  // all reads of Ks/Vt done before next stage
  }

  // ---- epilogue: O / l ----
  ushort* obase = out + (tok0 + q0) * 2048 + h * 128;
#pragma unroll
  for (int mt = 0; mt < 2; ++mt) {
#pragma unroll
    for (int r = 0; r < 4; ++r) {
      const int qrow = wq + mt * 16 + quad * 4 + r;
      const float inv = 1.f / l_run[mt * 4 + r];
#pragma unroll
      for (int nt = 0; nt < 8; ++nt)
        obase[(size_t)qrow * 2048 + nt * 16 + lm] = f2bf(o[mt][nt][r] * inv);
    }
  }
}

// ---------------- act = silu(g) * u ----------------
__global__ __launch_bounds__(256)
void silu_mul(ushort* __restrict__ g, const ushort* __restrict__ u, size_t n8) {
  size_t i = (size_t)blockIdx.x * 256 + threadIdx.x;
  if (i >= n8) return;
  short8 gs = ((const short8*)g)[i];
  short8 us = ((const short8*)u)[i];
  short8 os;
#pragma unroll
  for (int j = 0; j < 8; ++j) {
    float gf = bf2f((ushort)gs[j]);
    float uf = bf2f((ushort)us[j]);
    float a = gf / (1.f + expf(-gf)) * uf;
    os[j] = (short)f2bf(a);
  }
  ((short8*)g)[i] = os;
}

extern "C" void kernel_launch(void* const* d_in, const int* in_sizes, int n_in,
                              void* d_out, int out_size, void* d_ws, size_t ws_size,
                              hipStream_t stream) {
  const float* hidden = (const float*)d_in[0];
  const int*   pos    = (const int*)d_in[1];
  const float* Wq     = (const float*)d_in[2];
  const float* Wkva   = (const float*)d_in[3];
  const float* w_kvln = (const float*)d_in[4];
  const float* Wkvb   = (const float*)d_in[5];
  const float* Wo     = (const float*)d_in[6];
  const float* Wg     = (const float*)d_in[7];
  const float* Wu     = (const float*)d_in[8];
  const float* Wd     = (const float*)d_in[9];
  const float* w_ln1  = (const float*)d_in[10];
  const float* w_ln2  = (const float*)d_in[11];
  float* out = (float*)d_out;

  char* ws = (char*)d_ws;
  ushort* xn    = (ushort*)(ws);
  char*   R1    = ws + 16777216;
  ushort* qb    = (ushort*)(R1);
  float*  ckv   = (float*)(R1 + 25165824);
  ushort* cn    = (ushort*)(R1 + 34603008);
  ushort* kvb   = (ushort*)(R1 + 38797312);
  ushort* kpe   = (ushort*)(R1 + 72351744);
  ushort* attno = (ushort*)(R1 + 72876032);
  ushort* gb    = (ushort*)(R1);
  ushort* ub    = (ushort*)(ws + 106430464);
  float*  h1    = (float*)(ws + 196083712);

  rms_bf16<<<4096, 256, 0, stream>>>(hidden, 2048, 2048, 1.f / 2048.f, w_ln1, xn, 2048);
  gemm_nt<0><<<dim3(32, 24), 256, 0, stream>>>(xn, Wq, qb, nullptr, 4096, 3072, 2048);
  gemm_nt<1><<<dim3(32, 5), 256, 0, stream>>>(xn, Wkva, ckv, nullptr, 4096, 576, 2048);
  rms_bf16<<<4096, 256, 0, stream>>>(ckv, 576, 512, 1.f / 512.f, w_kvln, cn, 512);
  gemm_nt<0><<<dim3(32, 32), 256, 0, stream>>>(cn, Wkvb, kvb, nullptr, 4096, 4096, 512);
  rope_kernel<<<4096, 64, 0, stream>>>(qb, ckv, pos, kpe);
  attn_mfma<<<dim3(16, 32), 256, 0, stream>>>(qb, kvb, kpe, attno);
  gemm_nt<2><<<dim3(32, 16), 256, 0, stream>>>(attno, Wo, h1, hidden, 4096, 2048, 2048);
  rms_bf16<<<4096, 256, 0, stream>>>(h1, 2048, 2048, 1.f / 2048.f, w_ln2, xn, 2048);
  gemm_nt<0><<<dim3(32, 86), 256, 0, stream>>>(xn, Wg, gb, nullptr, 4096, 10944, 2048);
  gemm_nt<0><<<dim3(32, 86), 256, 0, stream>>>(xn, Wu, ub, nullptr, 4096, 10944, 2048);
  silu_mul<<<21888, 256, 0, stream>>>(gb, ub, (size_t)4096 * 10944 / 8);
  gemm_nt<2><<<dim3(32, 16), 256, 0, stream>>>(gb, Wd, out, h1, 4096, 2048, 10944);
}

// Round 3
// 1522.288 us; speedup vs baseline: 7.5302x; 3.6191x over previous
//
#include <hip/hip_runtime.h>
#include <hip/hip_bf16.h>
#include <math.h>

// DeepseekV2-Lite decoder layer, MI355X gfx950.
// Round 2: m97-structure GEMMs (global_load_lds width=16, bf16 weights
// pre-converted into workspace), silu fused into up-proj epilogue.
//
// Shapes: B=2 S=2048 T=4096, H=16, D_NOPE=128 D_ROPE=64 D_Q=192 D_V=128,
// KV_RANK=512, HID=2048, INTER=10944.
//
// Workspace (229,638,144 B total — same as round 1):
//  [0, 16.78M)        xn bf16 (T,2048)
//  [16.78M, +89.65M)  R1: qb|ckv|cn|kvb|kpe|attno ; later act g bf16 (T,10944)
//  [106.43M, +89.65M) weight slots:
//     phase A: wq_bf 12.58M | wkva_bf 2.36M | wkvb_bf 4.19M | wo_bf 8.39M | (wu_bf at +44.83M)
//     phase B: wg_bf 44.83M | wu_bf/wd_bf 44.83M
//  [196.08M, +33.55M) h1 f32 (T,2048)

typedef short short8 __attribute__((ext_vector_type(8)));
typedef short short4v __attribute__((ext_vector_type(4)));
typedef float f32x4 __attribute__((ext_vector_type(4)));

static __device__ __forceinline__ float bf2f(ushort u) {
  union { uint i; float f; } v; v.i = ((uint)u) << 16; return v.f;
}
static __device__ __forceinline__ ushort f2bf(float x) {
  union { float f; uint i; } v; v.f = x;
  uint r = v.i + 0x7fffu + ((v.i >> 16) & 1u);
  return (ushort)(r >> 16);
}

// async global->LDS, 16B per lane; LDS dest is wave-uniform base + lane*16
static __device__ __forceinline__ void glds16(const ushort* g, ushort* l) {
  __builtin_amdgcn_global_load_lds(
      (const __attribute__((address_space(1))) unsigned int*)g,
      (__attribute__((address_space(3))) unsigned int*)l, 16, 0, 0);
}

// ---------------- fp32 -> bf16 weight conversion ----------------
__global__ __launch_bounds__(256)
void cvt_bf16(const float* __restrict__ in, ushort* __restrict__ out, int n8) {
  int i = blockIdx.x * 256 + threadIdx.x;
  if (i >= n8) return;
  float4 a = ((const float4*)in)[2 * i];
  float4 b = ((const float4*)in)[2 * i + 1];
  short8 o;
  o[0] = (short)f2bf(a.x); o[1] = (short)f2bf(a.y);
  o[2] = (short)f2bf(a.z); o[3] = (short)f2bf(a.w);
  o[4] = (short)f2bf(b.x); o[5] = (short)f2bf(b.y);
  o[6] = (short)f2bf(b.z); o[7] = (short)f2bf(b.w);
  ((short8*)out)[i] = o;
}

// ---------------- RMSNorm (fp32 in -> bf16 out) ----------------
__global__ __launch_bounds__(256)
void rms_bf16(const float* __restrict__ in, int istride, int width, float inv_w,
              const float* __restrict__ w, ushort* __restrict__ out, int ostride) {
  const int row = blockIdx.x;
  const float* x = in + (size_t)row * istride;
  float ss = 0.f;
  for (int i = threadIdx.x; i < width; i += 256) { float v = x[i]; ss += v * v; }
#pragma unroll
  for (int off = 32; off > 0; off >>= 1) ss += __shfl_xor(ss, off);
  __shared__ float red[4];
  if ((threadIdx.x & 63) == 0) red[threadIdx.x >> 6] = ss;
  __syncthreads();
  float tot = red[0] + red[1] + red[2] + red[3];
  float scale = rsqrtf(tot * inv_w + 1e-6f);
  ushort* o = out + (size_t)row * ostride;
  for (int i = threadIdx.x; i < width; i += 256) o[i] = f2bf(x[i] * scale * w[i]);
}

// ---------------- m97 GEMM: C[M,N] = A[M,K](bf16) @ B[N,K]^T(bf16) ----------------
// EPI 0: C bf16
// EPI 1: C f32
// EPI 2: C f32 = acc + res(f32)
// EPI 3: C bf16 = silu(prev bf16 at same addr) * acc   (resv = prev = Cv)
template<int EPI>
__global__ __launch_bounds__(256, 2)
void gemm_as(const ushort* __restrict__ A, const ushort* __restrict__ B,
             void* __restrict__ Cv, const void* __restrict__ resv,
             int M, int N, int K) {
  __shared__ ushort As[128 * 32];   // unpadded: global_load_lds layout
  __shared__ ushort Bs[128 * 32];
  const int tid = threadIdx.x;
  const int wave = tid >> 6, lane = tid & 63;
  const int m0 = blockIdx.x * 128, n0 = blockIdx.y * 128;
  const int lm = lane & 15, quad = lane >> 4;
  const int wm = (wave & 1) * 64, wn = (wave >> 1) * 64;

  // staging: wave w covers rows [w*32, w*32+32) of each tile, 2 insts of 16 rows
  const int srow = wave * 32 + (lane >> 2);
  const int scol = (lane & 3) * 8;
  const ushort* gA0 = A + (size_t)(m0 + srow) * K + scol;
  const ushort* gA1 = A + (size_t)(m0 + srow + 16) * K + scol;
  int br0 = n0 + srow;      if (br0 > N - 1) br0 = N - 1;  // clamp OOB (garbage ok)
  int br1 = n0 + srow + 16; if (br1 > N - 1) br1 = N - 1;
  const ushort* gB0 = B + (size_t)br0 * K + scol;
  const ushort* gB1 = B + (size_t)br1 * K + scol;
  ushort* lA0 = &As[(wave * 32) * 32];        // wave-uniform LDS bases
  ushort* lA1 = &As[(wave * 32 + 16) * 32];
  ushort* lB0 = &Bs[(wave * 32) * 32];
  ushort* lB1 = &Bs[(wave * 32 + 16) * 32];

  f32x4 acc[4][4];
  const f32x4 z4 = {0.f, 0.f, 0.f, 0.f};
#pragma unroll
  for (int i = 0; i < 4; ++i)
#pragma unroll
    for (int j = 0; j < 4; ++j) acc[i][j] = z4;

  for (int k0 = 0; k0 < K; k0 += 32) {
    glds16(gA0 + k0, lA0);
    glds16(gA1 + k0, lA1);
    glds16(gB0 + k0, lB0);
    glds16(gB1 + k0, lB1);
    __syncthreads();  // drains vmcnt: tile visible to all waves

    short8 afr[4], bfr[4];
#pragma unroll
    for (int mt = 0; mt < 4; ++mt)
      afr[mt] = *(const short8*)&As[(wm + mt * 16 + lm) * 32 + quad * 8];
#pragma unroll
    for (int nt = 0; nt < 4; ++nt)
      bfr[nt] = *(const short8*)&Bs[(wn + nt * 16 + lm) * 32 + quad * 8];
#pragma unroll
    for (int mt = 0; mt < 4; ++mt)
#pragma unroll
      for (int nt = 0; nt < 4; ++nt)
        acc[mt][nt] = __builtin_amdgcn_mfma_f32_16x16x32_bf16(
            afr[mt], bfr[nt], acc[mt][nt], 0, 0, 0);
    __syncthreads();  // LDS reads done before next iter's DMA overwrites
  }

  // C/D layout: col = lane&15, row = quad*4 + r   [m89-verified]
#pragma unroll
  for (int mt = 0; mt < 4; ++mt) {
#pragma unroll
    for (int r = 0; r < 4; ++r) {
      const int grow = m0 + wm + mt * 16 + quad * 4 + r;
#pragma unroll
      for (int nt = 0; nt < 4; ++nt) {
        const int gcol = n0 + wn + nt * 16 + lm;
        if (gcol < N) {
          const size_t idx = (size_t)grow * N + gcol;
          float vacc = acc[mt][nt][r];
          if (EPI == 0) {
            ((ushort*)Cv)[idx] = f2bf(vacc);
          } else if (EPI == 1) {
            ((float*)Cv)[idx] = vacc;
          } else if (EPI == 2) {
            ((float*)Cv)[idx] = vacc + ((const float*)resv)[idx];
          } else {
            float gv = bf2f(((const ushort*)resv)[idx]);
            ((ushort*)Cv)[idx] = f2bf(gv / (1.f + expf(-gv)) * vacc);
          }
        }
      }
    }
  }
}

// ---------------- YaRN RoPE ----------------
__global__ __launch_bounds__(64)
void rope_kernel(ushort* __restrict__ q, const float* __restrict__ ckv,
                 const int* __restrict__ pos_ids, ushort* __restrict__ kpe) {
  const int t = blockIdx.x;
  const int j = threadIdx.x;
  const int j2 = j & 31;
  const float ar = (float)j2 * (1.f / 32.f);
  const float fe = exp2f(-ar * 13.287712379549449f);
  const float fi = fe * 0.025f;
  float ramp = ((float)j2 - 10.f) * (1.f / 13.f);
  ramp = fminf(fmaxf(ramp, 0.f), 1.f);
  const float invf = fi * ramp + fe * (1.f - ramp);
  const float ang = (float)pos_ids[t] * invf;
  const float c = cosf(ang), s = sinf(ang);
  const bool lo = j < 32;
  {
    const float* kp = ckv + (size_t)t * 576 + 512;
    float x0 = kp[2 * j2], x1 = kp[2 * j2 + 1];
    float o = lo ? (x0 * c - x1 * s) : (x1 * c + x0 * s);
    kpe[(size_t)t * 64 + j] = f2bf(o);
  }
  for (int h = 0; h < 16; ++h) {
    ushort* qp = q + (size_t)t * 3072 + h * 192 + 128;
    float x0 = bf2f(qp[2 * j2]), x1 = bf2f(qp[2 * j2 + 1]);
    float o = lo ? (x0 * c - x1 * s) : (x1 * c + x0 * s);
    __syncthreads();
    qp[j] = f2bf(o);
  }
}

// ---------------- Flash MFMA attention (unchanged from round 1) ----------------
__global__ __launch_bounds__(256, 2)
void attn_mfma(const ushort* __restrict__ q, const ushort* __restrict__ kv,
               const ushort* __restrict__ kpe, ushort* __restrict__ out) {
  const int qt = (int)gridDim.x - 1 - (int)blockIdx.x;
  const int bh = blockIdx.y;
  const int b = bh >> 4, h = bh & 15;
  const int tid = threadIdx.x;
  const int wave = tid >> 6, lane = tid & 63;
  const int lm = lane & 15, quad = lane >> 4;
  const int wq = wave * 32;
  const float scale = 0.07216878364870323f;

  __shared__ __align__(16) char smem[62464];
  ushort (*Ks)[200] = (ushort(*)[200])smem;
  ushort (*Vt)[72]  = (ushort(*)[72])(smem + 25600);
  ushort (*Pm)[72]  = (ushort(*)[72])(smem + 44032);
  ushort (*Qs)[200] = (ushort(*)[200])smem;

  const size_t tok0 = (size_t)b * 2048;
  const int q0 = qt * 128;

  {
    const ushort* qbase = q + (tok0 + q0) * 3072 + (size_t)h * 192;
#pragma unroll
    for (int it = 0; it < 12; ++it) {
      int idx = (it * 256 + tid) * 8;
      int row = idx / 192, col = idx % 192;
      *(uint4*)&Qs[row][col] = *(const uint4*)(qbase + (size_t)row * 3072 + col);
    }
  }
  __syncthreads();
  short8 qf[2][6];
#pragma unroll
  for (int mt = 0; mt < 2; ++mt)
#pragma unroll
    for (int kk = 0; kk < 6; ++kk)
      qf[mt][kk] = *(const short8*)&Qs[wq + mt * 16 + lm][kk * 32 + quad * 8];
  __syncthreads();

  f32x4 o[2][8];
  const f32x4 z4 = {0.f, 0.f, 0.f, 0.f};
#pragma unroll
  for (int mt = 0; mt < 2; ++mt)
#pragma unroll
    for (int nt = 0; nt < 8; ++nt) o[mt][nt] = z4;
  float m_run[8], l_run[8];
#pragma unroll
  for (int i = 0; i < 8; ++i) { m_run[i] = -3.0e38f; l_run[i] = 0.f; }

  const int nkt = 2 * qt + 2;
  for (int kt = 0; kt < nkt; ++kt) {
    const int kb = kt * 64;
    {
      const int krow = tid >> 2, kq = tid & 3;
      const ushort* src = kv + ((tok0 + kb + krow) * 16 + h) * 256 + kq * 32;
#pragma unroll
      for (int i = 0; i < 4; ++i)
        *(uint4*)&Ks[krow][kq * 32 + i * 8] = *(const uint4*)(src + i * 8);
      const ushort* psrc = kpe + (tok0 + kb + krow) * 64 + kq * 16;
      *(uint4*)&Ks[krow][128 + kq * 16]     = *(const uint4*)(psrc);
      *(uint4*)&Ks[krow][128 + kq * 16 + 8] = *(const uint4*)(psrc + 8);
      const int kgrp = (tid & 15) * 4, dgrp = (tid >> 4) * 8;
      uint4 vv[4];
#pragma unroll
      for (int i = 0; i < 4; ++i)
        vv[i] = *(const uint4*)(kv + ((tok0 + kb + kgrp + i) * 16 + h) * 256 + 128 + dgrp);
#pragma unroll
      for (int j = 0; j < 8; ++j) {
        short4v w;
#pragma unroll
        for (int i = 0; i < 4; ++i) w[i] = (short)((const ushort*)&vv[i])[j];
        *(short4v*)&Vt[dgrp + j][kgrp] = w;
      }
    }
    __syncthreads();

    f32x4 s_acc[2][4];
#pragma unroll
    for (int mt = 0; mt < 2; ++mt)
#pragma unroll
      for (int nt = 0; nt < 4; ++nt) s_acc[mt][nt] = z4;
#pragma unroll
    for (int kk = 0; kk < 6; ++kk) {
      short8 kf[4];
#pragma unroll
      for (int nt = 0; nt < 4; ++nt)
        kf[nt] = *(const short8*)&Ks[nt * 16 + lm][kk * 32 + quad * 8];
#pragma unroll
      for (int mt = 0; mt < 2; ++mt)
#pragma unroll
        for (int nt = 0; nt < 4; ++nt)
          s_acc[mt][nt] = __builtin_amdgcn_mfma_f32_16x16x32_bf16(
              qf[mt][kk], kf[nt], s_acc[mt][nt], 0, 0, 0);
    }

#pragma unroll
    for (int mt = 0; mt < 2; ++mt) {
#pragma unroll
      for (int r = 0; r < 4; ++r) {
        const int qg = q0 + wq + mt * 16 + quad * 4 + r;
        float sv[4];
        float rm = -3.0e38f;
#pragma unroll
        for (int nt = 0; nt < 4; ++nt) {
          const int key = kb + nt * 16 + lm;
          float s = s_acc[mt][nt][r] * scale;
          s = (key <= qg) ? s : -3.0e38f;
          sv[nt] = s;
          rm = fmaxf(rm, s);
        }
#pragma unroll
        for (int off = 1; off < 16; off <<= 1) rm = fmaxf(rm, __shfl_xor(rm, off));
        const int li = mt * 4 + r;
        const float mnew = fmaxf(m_run[li], rm);
        const float alpha = expf(m_run[li] - mnew);
        m_run[li] = mnew;
        float rs = 0.f;
        ushort pb[4];
#pragma unroll
        for (int nt = 0; nt < 4; ++nt) {
          float p = expf(sv[nt] - mnew);
          rs += p;
          pb[nt] = f2bf(p);
        }
#pragma unroll
        for (int off = 1; off < 16; off <<= 1) rs += __shfl_xor(rs, off);
        l_run[li] = l_run[li] * alpha + rs;
#pragma unroll
        for (int nt = 0; nt < 8; ++nt) o[mt][nt][r] *= alpha;
        const int qrow = wq + mt * 16 + quad * 4 + r;
#pragma unroll
        for (int nt = 0; nt < 4; ++nt) Pm[qrow][nt * 16 + lm] = pb[nt];
      }
    }

#pragma unroll
    for (int kt2 = 0; kt2 < 2; ++kt2) {
      short8 pa[2];
#pragma unroll
      for (int mt = 0; mt < 2; ++mt)
        pa[mt] = *(const short8*)&Pm[wq + mt * 16 + lm][kt2 * 32 + quad * 8];
#pragma unroll
      for (int nt = 0; nt < 8; ++nt) {
        short8 vb = *(const short8*)&Vt[nt * 16 + lm][kt2 * 32 + quad * 8];
#pragma unroll
        for (int mt = 0; mt < 2; ++mt)
          o[mt][nt] = __builtin_amdgcn_mfma_f32_16x16x32_bf16(
              pa[mt], vb, o[mt][nt], 0, 0, 0);
      }
    }
    __syncthreads();
  }

  ushort* obase = out + (tok0 + q0) * 2048 + h * 128;
#pragma unroll
  for (int mt = 0; mt < 2; ++mt) {
#pragma unroll
    for (int r = 0; r < 4; ++r) {
      const int qrow = wq + mt * 16 + quad * 4 + r;
      const float inv = 1.f / l_run[mt * 4 + r];
#pragma unroll
      for (int nt = 0; nt < 8; ++nt)
        obase[(size_t)qrow * 2048 + nt * 16 + lm] = f2bf(o[mt][nt][r] * inv);
    }
  }
}

extern "C" void kernel_launch(void* const* d_in, const int* in_sizes, int n_in,
                              void* d_out, int out_size, void* d_ws, size_t ws_size,
                              hipStream_t stream) {
  const float* hidden = (const float*)d_in[0];
  const int*   pos    = (const int*)d_in[1];
  const float* Wq     = (const float*)d_in[2];
  const float* Wkva   = (const float*)d_in[3];
  const float* w_kvln = (const float*)d_in[4];
  const float* Wkvb   = (const float*)d_in[5];
  const float* Wo     = (const float*)d_in[6];
  const float* Wg     = (const float*)d_in[7];
  const float* Wu     = (const float*)d_in[8];
  const float* Wd     = (const float*)d_in[9];
  const float* w_ln1  = (const float*)d_in[10];
  const float* w_ln2  = (const float*)d_in[11];
  float* out = (float*)d_out;

  char* ws = (char*)d_ws;
  ushort* xn    = (ushort*)(ws);
  char*   R1    = ws + 16777216;
  ushort* qb    = (ushort*)(R1);
  float*  ckv   = (float*)(R1 + 25165824);
  ushort* cn    = (ushort*)(R1 + 34603008);
  ushort* kvb   = (ushort*)(R1 + 38797312);
  ushort* kpe   = (ushort*)(R1 + 72351744);
  ushort* attno = (ushort*)(R1 + 72876032);
  ushort* gb    = (ushort*)(R1);                    // (T,10944) aliases R1
  float*  h1    = (float*)(ws + 196083712);

  char* WSL = ws + 106430464;                       // 89,653,248 B slot region
  ushort* wq_bf   = (ushort*)(WSL);                 // 12,582,912
  ushort* wkva_bf = (ushort*)(WSL + 12582912);      //  2,359,296
  ushort* wkvb_bf = (ushort*)(WSL + 14942208);      //  4,194,304
  ushort* wo_bf   = (ushort*)(WSL + 19136512);      //  8,388,608
  ushort* wg_bf   = (ushort*)(WSL);                 // 44,826,624 (phase B)
  ushort* wu_bf   = (ushort*)(WSL + 44826624);      // 44,826,624
  ushort* wd_bf   = (ushort*)(WSL + 44826624);      // reuses wu slot after up GEMM

  // phase-A weight conversions (+ Wu which lives in the back half, free now)
  cvt_bf16<<<3072, 256, 0, stream>>>(Wq,   wq_bf,   786432);
  cvt_bf16<<<576,  256, 0, stream>>>(Wkva, wkva_bf, 147456);
  cvt_bf16<<<1024, 256, 0, stream>>>(Wkvb, wkvb_bf, 262144);
  cvt_bf16<<<2048, 256, 0, stream>>>(Wo,   wo_bf,   524288);
  cvt_bf16<<<10944, 256, 0, stream>>>(Wu,  wu_bf,   2801664);

  rms_bf16<<<4096, 256, 0, stream>>>(hidden, 2048, 2048, 1.f / 2048.f, w_ln1, xn, 2048);
  gemm_as<0><<<dim3(32, 24), 256, 0, stream>>>(xn, wq_bf, qb, nullptr, 4096, 3072, 2048);
  gemm_as<1><<<dim3(32, 5), 256, 0, stream>>>(xn, wkva_bf, ckv, nullptr, 4096, 576, 2048);
  rms_bf16<<<4096, 256, 0, stream>>>(ckv, 576, 512, 1.f / 512.f, w_kvln, cn, 512);
  gemm_as<0><<<dim3(32, 32), 256, 0, stream>>>(cn, wkvb_bf, kvb, nullptr, 4096, 4096, 512);
  rope_kernel<<<4096, 64, 0, stream>>>(qb, ckv, pos, kpe);
  attn_mfma<<<dim3(16, 32), 256, 0, stream>>>(qb, kvb, kpe, attno);
  gemm_as<2><<<dim3(32, 16), 256, 0, stream>>>(attno, wo_bf, h1, hidden, 4096, 2048, 2048);
  rms_bf16<<<4096, 256, 0, stream>>>(h1, 2048, 2048, 1.f / 2048.f, w_ln2, xn, 2048);

  // phase B: Wg conversion reuses the (now dead) phase-A front slots
  cvt_bf16<<<10944, 256, 0, stream>>>(Wg, wg_bf, 2801664);
  gemm_as<0><<<dim3(32, 86), 256, 0, stream>>>(xn, wg_bf, gb, nullptr, 4096, 10944, 2048);
  // up-proj with fused silu: act = silu(g) * (xn @ Wu^T), written over g
  gemm_as<3><<<dim3(32, 86), 256, 0, stream>>>(xn, wu_bf, gb, gb, 4096, 10944, 2048);
  // Wd conversion reuses the wu slot (dead after up GEMM)
  cvt_bf16<<<10944, 256, 0, stream>>>(Wd, wd_bf, 2801664);
  gemm_as<2><<<dim3(32, 16), 256, 0, stream>>>(gb, wd_bf, out, h1, 4096, 2048, 10944);
}

// Round 4
// 1403.205 us; speedup vs baseline: 8.1692x; 1.0849x over previous
//
#include <hip/hip_runtime.h>
#include <hip/hip_bf16.h>
#include <math.h>

// DeepseekV2-Lite decoder layer, MI355X gfx950.
// Round 4: GEMM K-loop restructured — BK=64 (32 MFMA per barrier pair) +
// XOR-swizzled LDS tiles to eliminate ds_read_b128 bank conflicts
// (global_load_lds forbids padding; swizzle the 16B units instead).
//
// Shapes: B=2 S=2048 T=4096, H=16, D_NOPE=128 D_ROPE=64 D_Q=192 D_V=128,
// KV_RANK=512, HID=2048, INTER=10944.

typedef short short8 __attribute__((ext_vector_type(8)));
typedef short short4v __attribute__((ext_vector_type(4)));
typedef float f32x4 __attribute__((ext_vector_type(4)));

static __device__ __forceinline__ float bf2f(ushort u) {
  union { uint i; float f; } v; v.i = ((uint)u) << 16; return v.f;
}
static __device__ __forceinline__ ushort f2bf(float x) {
  union { float f; uint i; } v; v.f = x;
  uint r = v.i + 0x7fffu + ((v.i >> 16) & 1u);
  return (ushort)(r >> 16);
}

// async global->LDS, 16B per lane; LDS dest is wave-uniform base + lane*16
static __device__ __forceinline__ void glds16(const ushort* g, ushort* l) {
  __builtin_amdgcn_global_load_lds(
      (const __attribute__((address_space(1))) unsigned int*)g,
      (__attribute__((address_space(3))) unsigned int*)l, 16, 0, 0);
}

// ---------------- fp32 -> bf16 weight conversion ----------------
__global__ __launch_bounds__(256)
void cvt_bf16(const float* __restrict__ in, ushort* __restrict__ out, int n8) {
  int i = blockIdx.x * 256 + threadIdx.x;
  if (i >= n8) return;
  float4 a = ((const float4*)in)[2 * i];
  float4 b = ((const float4*)in)[2 * i + 1];
  short8 o;
  o[0] = (short)f2bf(a.x); o[1] = (short)f2bf(a.y);
  o[2] = (short)f2bf(a.z); o[3] = (short)f2bf(a.w);
  o[4] = (short)f2bf(b.x); o[5] = (short)f2bf(b.y);
  o[6] = (short)f2bf(b.z); o[7] = (short)f2bf(b.w);
  ((short8*)out)[i] = o;
}

// ---------------- RMSNorm (fp32 in -> bf16 out) ----------------
__global__ __launch_bounds__(256)
void rms_bf16(const float* __restrict__ in, int istride, int width, float inv_w,
              const float* __restrict__ w, ushort* __restrict__ out, int ostride) {
  const int row = blockIdx.x;
  const float* x = in + (size_t)row * istride;
  float ss = 0.f;
  for (int i = threadIdx.x; i < width; i += 256) { float v = x[i]; ss += v * v; }
#pragma unroll
  for (int off = 32; off > 0; off >>= 1) ss += __shfl_xor(ss, off);
  __shared__ float red[4];
  if ((threadIdx.x & 63) == 0) red[threadIdx.x >> 6] = ss;
  __syncthreads();
  float tot = red[0] + red[1] + red[2] + red[3];
  float scale = rsqrtf(tot * inv_w + 1e-6f);
  ushort* o = out + (size_t)row * ostride;
  for (int i = threadIdx.x; i < width; i += 256) o[i] = f2bf(x[i] * scale * w[i]);
}

// ---------------- GEMM: C[M,N] = A[M,K](bf16) @ B[N,K]^T(bf16) ----------------
// BK=64, XOR-swizzled LDS: slot (row, s) holds global 16B-unit s ^ (row & 7).
// EPI 0: C bf16 ; EPI 1: C f32 ; EPI 2: C f32 = acc + res(f32)
// EPI 3: C bf16 = silu(prev bf16 at Cv) * acc
template<int EPI>
__global__ __launch_bounds__(256, 2)
void gemm_as(const ushort* __restrict__ A, const ushort* __restrict__ B,
             void* __restrict__ Cv, const void* __restrict__ resv,
             int M, int N, int K) {
  __shared__ ushort As[128 * 64];   // 16 KB
  __shared__ ushort Bs[128 * 64];   // 16 KB
  const int tid = threadIdx.x;
  const int wave = tid >> 6, lane = tid & 63;
  const int m0 = blockIdx.x * 128, n0 = blockIdx.y * 128;
  const int lm = lane & 15, quad = lane >> 4;
  const int wm = (wave & 1) * 64, wn = (wave >> 1) * 64;

  // staging: wave w covers tile rows [w*32, w*32+32), 4 insts x 8 rows each.
  // lane -> (lrow = lane>>3, lcq = lane&7); LDS slot lcq holds global unit
  // lcq ^ lrow  (row & 7 == lrow for every inst since j*8 is 8-aligned).
  const int lrow = lane >> 3;
  const int lcq  = lane & 7;
  const int gu   = lcq ^ lrow;
  const ushort* gA[4];
  const ushort* gB[4];
  ushort* lA[4];
  ushort* lB[4];
#pragma unroll
  for (int j = 0; j < 4; ++j) {
    const int r = wave * 32 + j * 8 + lrow;
    gA[j] = A + (size_t)(m0 + r) * K + gu * 8;
    int br = n0 + r; if (br > N - 1) br = N - 1;   // clamp OOB (garbage ok, cols guarded)
    gB[j] = B + (size_t)br * K + gu * 8;
    lA[j] = &As[(wave * 32 + j * 8) * 64];
    lB[j] = &Bs[(wave * 32 + j * 8) * 64];
  }

  f32x4 acc[4][4];
  const f32x4 z4 = {0.f, 0.f, 0.f, 0.f};
#pragma unroll
  for (int i = 0; i < 4; ++i)
#pragma unroll
    for (int j = 0; j < 4; ++j) acc[i][j] = z4;

  const int sw = lm & 7;   // read-side XOR key (row & 7 == lm & 7 for fragments)

  for (int k0 = 0; k0 < K; k0 += 64) {
#pragma unroll
    for (int j = 0; j < 4; ++j) glds16(gA[j] + k0, lA[j]);
#pragma unroll
    for (int j = 0; j < 4; ++j) glds16(gB[j] + k0, lB[j]);
    __syncthreads();  // drains vmcnt: tile visible to all waves

#pragma unroll
    for (int kk = 0; kk < 2; ++kk) {
      const int us = ((kk * 4 + quad) ^ sw) * 8;
      short8 afr[4], bfr[4];
#pragma unroll
      for (int mt = 0; mt < 4; ++mt)
        afr[mt] = *(const short8*)&As[(wm + mt * 16 + lm) * 64 + us];
#pragma unroll
      for (int nt = 0; nt < 4; ++nt)
        bfr[nt] = *(const short8*)&Bs[(wn + nt * 16 + lm) * 64 + us];
#pragma unroll
      for (int mt = 0; mt < 4; ++mt)
#pragma unroll
        for (int nt = 0; nt < 4; ++nt)
          acc[mt][nt] = __builtin_amdgcn_mfma_f32_16x16x32_bf16(
              afr[mt], bfr[nt], acc[mt][nt], 0, 0, 0);
    }
    __syncthreads();  // LDS reads done before next iter's DMA overwrites
  }

  // C/D layout: col = lane&15, row = quad*4 + r   [m89-verified]
#pragma unroll
  for (int mt = 0; mt < 4; ++mt) {
#pragma unroll
    for (int r = 0; r < 4; ++r) {
      const int grow = m0 + wm + mt * 16 + quad * 4 + r;
#pragma unroll
      for (int nt = 0; nt < 4; ++nt) {
        const int gcol = n0 + wn + nt * 16 + lm;
        if (gcol < N) {
          const size_t idx = (size_t)grow * N + gcol;
          float vacc = acc[mt][nt][r];
          if (EPI == 0) {
            ((ushort*)Cv)[idx] = f2bf(vacc);
          } else if (EPI == 1) {
            ((float*)Cv)[idx] = vacc;
          } else if (EPI == 2) {
            ((float*)Cv)[idx] = vacc + ((const float*)resv)[idx];
          } else {
            float gv = bf2f(((const ushort*)resv)[idx]);
            ((ushort*)Cv)[idx] = f2bf(gv / (1.f + expf(-gv)) * vacc);
          }
        }
      }
    }
  }
}

// ---------------- YaRN RoPE ----------------
__global__ __launch_bounds__(64)
void rope_kernel(ushort* __restrict__ q, const float* __restrict__ ckv,
                 const int* __restrict__ pos_ids, ushort* __restrict__ kpe) {
  const int t = blockIdx.x;
  const int j = threadIdx.x;
  const int j2 = j & 31;
  const float ar = (float)j2 * (1.f / 32.f);
  const float fe = exp2f(-ar * 13.287712379549449f);
  const float fi = fe * 0.025f;
  float ramp = ((float)j2 - 10.f) * (1.f / 13.f);
  ramp = fminf(fmaxf(ramp, 0.f), 1.f);
  const float invf = fi * ramp + fe * (1.f - ramp);
  const float ang = (float)pos_ids[t] * invf;
  const float c = cosf(ang), s = sinf(ang);
  const bool lo = j < 32;
  {
    const float* kp = ckv + (size_t)t * 576 + 512;
    float x0 = kp[2 * j2], x1 = kp[2 * j2 + 1];
    float o = lo ? (x0 * c - x1 * s) : (x1 * c + x0 * s);
    kpe[(size_t)t * 64 + j] = f2bf(o);
  }
  for (int h = 0; h < 16; ++h) {
    ushort* qp = q + (size_t)t * 3072 + h * 192 + 128;
    float x0 = bf2f(qp[2 * j2]), x1 = bf2f(qp[2 * j2 + 1]);
    float o = lo ? (x0 * c - x1 * s) : (x1 * c + x0 * s);
    __syncthreads();
    qp[j] = f2bf(o);
  }
}

// ---------------- Flash MFMA attention ----------------
__global__ __launch_bounds__(256, 2)
void attn_mfma(const ushort* __restrict__ q, const ushort* __restrict__ kv,
               const ushort* __restrict__ kpe, ushort* __restrict__ out) {
  const int qt = (int)gridDim.x - 1 - (int)blockIdx.x;
  const int bh = blockIdx.y;
  const int b = bh >> 4, h = bh & 15;
  const int tid = threadIdx.x;
  const int wave = tid >> 6, lane = tid & 63;
  const int lm = lane & 15, quad = lane >> 4;
  const int wq = wave * 32;
  const float scale = 0.07216878364870323f;

  __shared__ __align__(16) char smem[62464];
  ushort (*Ks)[200] = (ushort(*)[200])smem;
  ushort (*Vt)[72]  = (ushort(*)[72])(smem + 25600);
  ushort (*Pm)[72]  = (ushort(*)[72])(smem + 44032);
  ushort (*Qs)[200] = (ushort(*)[200])smem;

  const size_t tok0 = (size_t)b * 2048;
  const int q0 = qt * 128;

  {
    const ushort* qbase = q + (tok0 + q0) * 3072 + (size_t)h * 192;
#pragma unroll
    for (int it = 0; it < 12; ++it) {
      int idx = (it * 256 + tid) * 8;
      int row = idx / 192, col = idx % 192;
      *(uint4*)&Qs[row][col] = *(const uint4*)(qbase + (size_t)row * 3072 + col);
    }
  }
  __syncthreads();
  short8 qf[2][6];
#pragma unroll
  for (int mt = 0; mt < 2; ++mt)
#pragma unroll
    for (int kk = 0; kk < 6; ++kk)
      qf[mt][kk] = *(const short8*)&Qs[wq + mt * 16 + lm][kk * 32 + quad * 8];
  __syncthreads();

  f32x4 o[2][8];
  const f32x4 z4 = {0.f, 0.f, 0.f, 0.f};
#pragma unroll
  for (int mt = 0; mt < 2; ++mt)
#pragma unroll
    for (int nt = 0; nt < 8; ++nt) o[mt][nt] = z4;
  float m_run[8], l_run[8];
#pragma unroll
  for (int i = 0; i < 8; ++i) { m_run[i] = -3.0e38f; l_run[i] = 0.f; }

  const int nkt = 2 * qt + 2;
  for (int kt = 0; kt < nkt; ++kt) {
    const int kb = kt * 64;
    {
      const int krow = tid >> 2, kq = tid & 3;
      const ushort* src = kv + ((tok0 + kb + krow) * 16 + h) * 256 + kq * 32;
#pragma unroll
      for (int i = 0; i < 4; ++i)
        *(uint4*)&Ks[krow][kq * 32 + i * 8] = *(const uint4*)(src + i * 8);
      const ushort* psrc = kpe + (tok0 + kb + krow) * 64 + kq * 16;
      *(uint4*)&Ks[krow][128 + kq * 16]     = *(const uint4*)(psrc);
      *(uint4*)&Ks[krow][128 + kq * 16 + 8] = *(const uint4*)(psrc + 8);
      const int kgrp = (tid & 15) * 4, dgrp = (tid >> 4) * 8;
      uint4 vv[4];
#pragma unroll
      for (int i = 0; i < 4; ++i)
        vv[i] = *(const uint4*)(kv + ((tok0 + kb + kgrp + i) * 16 + h) * 256 + 128 + dgrp);
#pragma unroll
      for (int j = 0; j < 8; ++j) {
        short4v w;
#pragma unroll
        for (int i = 0; i < 4; ++i) w[i] = (short)((const ushort*)&vv[i])[j];
        *(short4v*)&Vt[dgrp + j][kgrp] = w;
      }
    }
    __syncthreads();

    f32x4 s_acc[2][4];
#pragma unroll
    for (int mt = 0; mt < 2; ++mt)
#pragma unroll
      for (int nt = 0; nt < 4; ++nt) s_acc[mt][nt] = z4;
#pragma unroll
    for (int kk = 0; kk < 6; ++kk) {
      short8 kf[4];
#pragma unroll
      for (int nt = 0; nt < 4; ++nt)
        kf[nt] = *(const short8*)&Ks[nt * 16 + lm][kk * 32 + quad * 8];
#pragma unroll
      for (int mt = 0; mt < 2; ++mt)
#pragma unroll
        for (int nt = 0; nt < 4; ++nt)
          s_acc[mt][nt] = __builtin_amdgcn_mfma_f32_16x16x32_bf16(
              qf[mt][kk], kf[nt], s_acc[mt][nt], 0, 0, 0);
    }

#pragma unroll
    for (int mt = 0; mt < 2; ++mt) {
#pragma unroll
      for (int r = 0; r < 4; ++r) {
        const int qg = q0 + wq + mt * 16 + quad * 4 + r;
        float sv[4];
        float rm = -3.0e38f;
#pragma unroll
        for (int nt = 0; nt < 4; ++nt) {
          const int key = kb + nt * 16 + lm;
          float s = s_acc[mt][nt][r] * scale;
          s = (key <= qg) ? s : -3.0e38f;
          sv[nt] = s;
          rm = fmaxf(rm, s);
        }
#pragma unroll
        for (int off = 1; off < 16; off <<= 1) rm = fmaxf(rm, __shfl_xor(rm, off));
        const int li = mt * 4 + r;
        const float mnew = fmaxf(m_run[li], rm);
        const float alpha = expf(m_run[li] - mnew);
        m_run[li] = mnew;
        float rs = 0.f;
        ushort pb[4];
#pragma unroll
        for (int nt = 0; nt < 4; ++nt) {
          float p = expf(sv[nt] - mnew);
          rs += p;
          pb[nt] = f2bf(p);
        }
#pragma unroll
        for (int off = 1; off < 16; off <<= 1) rs += __shfl_xor(rs, off);
        l_run[li] = l_run[li] * alpha + rs;
#pragma unroll
        for (int nt = 0; nt < 8; ++nt) o[mt][nt][r] *= alpha;
        const int qrow = wq + mt * 16 + quad * 4 + r;
#pragma unroll
        for (int nt = 0; nt < 4; ++nt) Pm[qrow][nt * 16 + lm] = pb[nt];
      }
    }

#pragma unroll
    for (int kt2 = 0; kt2 < 2; ++kt2) {
      short8 pa[2];
#pragma unroll
      for (int mt = 0; mt < 2; ++mt)
        pa[mt] = *(const short8*)&Pm[wq + mt * 16 + lm][kt2 * 32 + quad * 8];
#pragma unroll
      for (int nt = 0; nt < 8; ++nt) {
        short8 vb = *(const short8*)&Vt[nt * 16 + lm][kt2 * 32 + quad * 8];
#pragma unroll
        for (int mt = 0; mt < 2; ++mt)
          o[mt][nt] = __builtin_amdgcn_mfma_f32_16x16x32_bf16(
              pa[mt], vb, o[mt][nt], 0, 0, 0);
      }
    }
    __syncthreads();
  }

  ushort* obase = out + (tok0 + q0) * 2048 + h * 128;
#pragma unroll
  for (int mt = 0; mt < 2; ++mt) {
#pragma unroll
    for (int r = 0; r < 4; ++r) {
      const int qrow = wq + mt * 16 + quad * 4 + r;
      const float inv = 1.f / l_run[mt * 4 + r];
#pragma unroll
      for (int nt = 0; nt < 8; ++nt)
        obase[(size_t)qrow * 2048 + nt * 16 + lm] = f2bf(o[mt][nt][r] * inv);
    }
  }
}

extern "C" void kernel_launch(void* const* d_in, const int* in_sizes, int n_in,
                              void* d_out, int out_size, void* d_ws, size_t ws_size,
                              hipStream_t stream) {
  const float* hidden = (const float*)d_in[0];
  const int*   pos    = (const int*)d_in[1];
  const float* Wq     = (const float*)d_in[2];
  const float* Wkva   = (const float*)d_in[3];
  const float* w_kvln = (const float*)d_in[4];
  const float* Wkvb   = (const float*)d_in[5];
  const float* Wo     = (const float*)d_in[6];
  const float* Wg     = (const float*)d_in[7];
  const float* Wu     = (const float*)d_in[8];
  const float* Wd     = (const float*)d_in[9];
  const float* w_ln1  = (const float*)d_in[10];
  const float* w_ln2  = (const float*)d_in[11];
  float* out = (float*)d_out;

  char* ws = (char*)d_ws;
  ushort* xn    = (ushort*)(ws);
  char*   R1    = ws + 16777216;
  ushort* qb    = (ushort*)(R1);
  float*  ckv   = (float*)(R1 + 25165824);
  ushort* cn    = (ushort*)(R1 + 34603008);
  ushort* kvb   = (ushort*)(R1 + 38797312);
  ushort* kpe   = (ushort*)(R1 + 72351744);
  ushort* attno = (ushort*)(R1 + 72876032);
  ushort* gb    = (ushort*)(R1);                    // (T,10944) aliases R1
  float*  h1    = (float*)(ws + 196083712);

  char* WSL = ws + 106430464;                       // 89,653,248 B slot region
  ushort* wq_bf   = (ushort*)(WSL);
  ushort* wkva_bf = (ushort*)(WSL + 12582912);
  ushort* wkvb_bf = (ushort*)(WSL + 14942208);
  ushort* wo_bf   = (ushort*)(WSL + 19136512);
  ushort* wg_bf   = (ushort*)(WSL);                 // phase B
  ushort* wu_bf   = (ushort*)(WSL + 44826624);
  ushort* wd_bf   = (ushort*)(WSL + 44826624);      // reuses wu slot after up GEMM

  cvt_bf16<<<3072, 256, 0, stream>>>(Wq,   wq_bf,   786432);
  cvt_bf16<<<576,  256, 0, stream>>>(Wkva, wkva_bf, 147456);
  cvt_bf16<<<1024, 256, 0, stream>>>(Wkvb, wkvb_bf, 262144);
  cvt_bf16<<<2048, 256, 0, stream>>>(Wo,   wo_bf,   524288);
  cvt_bf16<<<10944, 256, 0, stream>>>(Wu,  wu_bf,   2801664);

  rms_bf16<<<4096, 256, 0, stream>>>(hidden, 2048, 2048, 1.f / 2048.f, w_ln1, xn, 2048);
  gemm_as<0><<<dim3(32, 24), 256, 0, stream>>>(xn, wq_bf, qb, nullptr, 4096, 3072, 2048);
  gemm_as<1><<<dim3(32, 5), 256, 0, stream>>>(xn, wkva_bf, ckv, nullptr, 4096, 576, 2048);
  rms_bf16<<<4096, 256, 0, stream>>>(ckv, 576, 512, 1.f / 512.f, w_kvln, cn, 512);
  gemm_as<0><<<dim3(32, 32), 256, 0, stream>>>(cn, wkvb_bf, kvb, nullptr, 4096, 4096, 512);
  rope_kernel<<<4096, 64, 0, stream>>>(qb, ckv, pos, kpe);
  attn_mfma<<<dim3(16, 32), 256, 0, stream>>>(qb, kvb, kpe, attno);
  gemm_as<2><<<dim3(32, 16), 256, 0, stream>>>(attno, wo_bf, h1, hidden, 4096, 2048, 2048);
  rms_bf16<<<4096, 256, 0, stream>>>(h1, 2048, 2048, 1.f / 2048.f, w_ln2, xn, 2048);

  cvt_bf16<<<10944, 256, 0, stream>>>(Wg, wg_bf, 2801664);
  gemm_as<0><<<dim3(32, 86), 256, 0, stream>>>(xn, wg_bf, gb, nullptr, 4096, 10944, 2048);
  gemm_as<3><<<dim3(32, 86), 256, 0, stream>>>(xn, wu_bf, gb, gb, 4096, 10944, 2048);
  cvt_bf16<<<10944, 256, 0, stream>>>(Wd, wd_bf, 2801664);
  gemm_as<2><<<dim3(32, 16), 256, 0, stream>>>(gb, wd_bf, out, h1, 4096, 2048, 10944);
}

// Round 5
// 1378.557 us; speedup vs baseline: 8.3153x; 1.0179x over previous
//
#include <hip/hip_runtime.h>
#include <hip/hip_bf16.h>
#include <math.h>

// DeepseekV2-Lite decoder layer, MI355X gfx950.
// Round 5: fast-math intrinsics (__expf / __sincosf) in attention softmax,
// silu epilogue, rope; wave-uniform causal fast path for interior k-tiles;
// Wq+Wkva merged into one GEMM (contiguous weight slots, split epilogue).
//
// Shapes: B=2 S=2048 T=4096, H=16, D_NOPE=128 D_ROPE=64 D_Q=192 D_V=128,
// KV_RANK=512, HID=2048, INTER=10944.

typedef short short8 __attribute__((ext_vector_type(8)));
typedef short short4v __attribute__((ext_vector_type(4)));
typedef float f32x4 __attribute__((ext_vector_type(4)));

static __device__ __forceinline__ float bf2f(ushort u) {
  union { uint i; float f; } v; v.i = ((uint)u) << 16; return v.f;
}
static __device__ __forceinline__ ushort f2bf(float x) {
  union { float f; uint i; } v; v.f = x;
  uint r = v.i + 0x7fffu + ((v.i >> 16) & 1u);
  return (ushort)(r >> 16);
}

// async global->LDS, 16B per lane; LDS dest is wave-uniform base + lane*16
static __device__ __forceinline__ void glds16(const ushort* g, ushort* l) {
  __builtin_amdgcn_global_load_lds(
      (const __attribute__((address_space(1))) unsigned int*)g,
      (__attribute__((address_space(3))) unsigned int*)l, 16, 0, 0);
}

// ---------------- fp32 -> bf16 weight conversion ----------------
__global__ __launch_bounds__(256)
void cvt_bf16(const float* __restrict__ in, ushort* __restrict__ out, int n8) {
  int i = blockIdx.x * 256 + threadIdx.x;
  if (i >= n8) return;
  float4 a = ((const float4*)in)[2 * i];
  float4 b = ((const float4*)in)[2 * i + 1];
  short8 o;
  o[0] = (short)f2bf(a.x); o[1] = (short)f2bf(a.y);
  o[2] = (short)f2bf(a.z); o[3] = (short)f2bf(a.w);
  o[4] = (short)f2bf(b.x); o[5] = (short)f2bf(b.y);
  o[6] = (short)f2bf(b.z); o[7] = (short)f2bf(b.w);
  ((short8*)out)[i] = o;
}

// ---------------- RMSNorm (fp32 in -> bf16 out) ----------------
__global__ __launch_bounds__(256)
void rms_bf16(const float* __restrict__ in, int istride, int width, float inv_w,
              const float* __restrict__ w, ushort* __restrict__ out, int ostride) {
  const int row = blockIdx.x;
  const float* x = in + (size_t)row * istride;
  float ss = 0.f;
  for (int i = threadIdx.x; i < width; i += 256) { float v = x[i]; ss += v * v; }
#pragma unroll
  for (int off = 32; off > 0; off >>= 1) ss += __shfl_xor(ss, off);
  __shared__ float red[4];
  if ((threadIdx.x & 63) == 0) red[threadIdx.x >> 6] = ss;
  __syncthreads();
  float tot = red[0] + red[1] + red[2] + red[3];
  float scale = rsqrtf(tot * inv_w + 1e-6f);
  ushort* o = out + (size_t)row * ostride;
  for (int i = threadIdx.x; i < width; i += 256) o[i] = f2bf(x[i] * scale * w[i]);
}

// ---------------- GEMM: C[M,N] = A[M,K](bf16) @ B[N,K]^T(bf16) ----------------
// BK=64, XOR-swizzled LDS: slot (row, s) holds global 16B-unit s ^ (row & 7).
// EPI 0: C bf16 ; EPI 1: C f32 ; EPI 2: C f32 = acc + res(f32)
// EPI 3: C bf16 = silu(prev bf16 at Cv) * acc
// EPI 4: split QKV epilogue — cols [0,3072) -> bf16 q (stride 3072);
//        cols [3072,3648) -> f32 ckv (stride 576), resv = ckv base
template<int EPI>
__global__ __launch_bounds__(256, 2)
void gemm_as(const ushort* __restrict__ A, const ushort* __restrict__ B,
             void* __restrict__ Cv, const void* __restrict__ resv,
             int M, int N, int K) {
  __shared__ ushort As[128 * 64];   // 16 KB
  __shared__ ushort Bs[128 * 64];   // 16 KB
  const int tid = threadIdx.x;
  const int wave = tid >> 6, lane = tid & 63;
  const int m0 = blockIdx.x * 128, n0 = blockIdx.y * 128;
  const int lm = lane & 15, quad = lane >> 4;
  const int wm = (wave & 1) * 64, wn = (wave >> 1) * 64;

  const int lrow = lane >> 3;
  const int lcq  = lane & 7;
  const int gu   = lcq ^ lrow;
  const ushort* gA[4];
  const ushort* gB[4];
  ushort* lA[4];
  ushort* lB[4];
#pragma unroll
  for (int j = 0; j < 4; ++j) {
    const int r = wave * 32 + j * 8 + lrow;
    gA[j] = A + (size_t)(m0 + r) * K + gu * 8;
    int br = n0 + r; if (br > N - 1) br = N - 1;   // clamp OOB (garbage ok, cols guarded)
    gB[j] = B + (size_t)br * K + gu * 8;
    lA[j] = &As[(wave * 32 + j * 8) * 64];
    lB[j] = &Bs[(wave * 32 + j * 8) * 64];
  }

  f32x4 acc[4][4];
  const f32x4 z4 = {0.f, 0.f, 0.f, 0.f};
#pragma unroll
  for (int i = 0; i < 4; ++i)
#pragma unroll
    for (int j = 0; j < 4; ++j) acc[i][j] = z4;

  const int sw = lm & 7;   // read-side XOR key

  for (int k0 = 0; k0 < K; k0 += 64) {
#pragma unroll
    for (int j = 0; j < 4; ++j) glds16(gA[j] + k0, lA[j]);
#pragma unroll
    for (int j = 0; j < 4; ++j) glds16(gB[j] + k0, lB[j]);
    __syncthreads();

#pragma unroll
    for (int kk = 0; kk < 2; ++kk) {
      const int us = ((kk * 4 + quad) ^ sw) * 8;
      short8 afr[4], bfr[4];
#pragma unroll
      for (int mt = 0; mt < 4; ++mt)
        afr[mt] = *(const short8*)&As[(wm + mt * 16 + lm) * 64 + us];
#pragma unroll
      for (int nt = 0; nt < 4; ++nt)
        bfr[nt] = *(const short8*)&Bs[(wn + nt * 16 + lm) * 64 + us];
#pragma unroll
      for (int mt = 0; mt < 4; ++mt)
#pragma unroll
        for (int nt = 0; nt < 4; ++nt)
          acc[mt][nt] = __builtin_amdgcn_mfma_f32_16x16x32_bf16(
              afr[mt], bfr[nt], acc[mt][nt], 0, 0, 0);
    }
    __syncthreads();
  }

  // C/D layout: col = lane&15, row = quad*4 + r   [m89-verified]
#pragma unroll
  for (int mt = 0; mt < 4; ++mt) {
#pragma unroll
    for (int r = 0; r < 4; ++r) {
      const int grow = m0 + wm + mt * 16 + quad * 4 + r;
#pragma unroll
      for (int nt = 0; nt < 4; ++nt) {
        const int gcol = n0 + wn + nt * 16 + lm;
        if (gcol < N) {
          const size_t idx = (size_t)grow * N + gcol;
          float vacc = acc[mt][nt][r];
          if (EPI == 0) {
            ((ushort*)Cv)[idx] = f2bf(vacc);
          } else if (EPI == 1) {
            ((float*)Cv)[idx] = vacc;
          } else if (EPI == 2) {
            ((float*)Cv)[idx] = vacc + ((const float*)resv)[idx];
          } else if (EPI == 3) {
            float gv = bf2f(((const ushort*)resv)[idx]);
            ((ushort*)Cv)[idx] = f2bf(gv / (1.f + __expf(-gv)) * vacc);
          } else {  // EPI 4: split q / ckv
            if (gcol < 3072)
              ((ushort*)Cv)[(size_t)grow * 3072 + gcol] = f2bf(vacc);
            else
              ((float*)resv)[(size_t)grow * 576 + (gcol - 3072)] = vacc;
          }
        }
      }
    }
  }
}

// ---------------- YaRN RoPE ----------------
__global__ __launch_bounds__(64)
void rope_kernel(ushort* __restrict__ q, const float* __restrict__ ckv,
                 const int* __restrict__ pos_ids, ushort* __restrict__ kpe) {
  const int t = blockIdx.x;
  const int j = threadIdx.x;
  const int j2 = j & 31;
  const float ar = (float)j2 * (1.f / 32.f);
  const float fe = exp2f(-ar * 13.287712379549449f);
  const float fi = fe * 0.025f;
  float ramp = ((float)j2 - 10.f) * (1.f / 13.f);
  ramp = fminf(fmaxf(ramp, 0.f), 1.f);
  const float invf = fi * ramp + fe * (1.f - ramp);
  const float ang = (float)pos_ids[t] * invf;
  float s, c;
  __sincosf(ang, &s, &c);
  const bool lo = j < 32;
  {
    const float* kp = ckv + (size_t)t * 576 + 512;
    float x0 = kp[2 * j2], x1 = kp[2 * j2 + 1];
    float o = lo ? (x0 * c - x1 * s) : (x1 * c + x0 * s);
    kpe[(size_t)t * 64 + j] = f2bf(o);
  }
  for (int h = 0; h < 16; ++h) {
    ushort* qp = q + (size_t)t * 3072 + h * 192 + 128;
    float x0 = bf2f(qp[2 * j2]), x1 = bf2f(qp[2 * j2 + 1]);
    float o = lo ? (x0 * c - x1 * s) : (x1 * c + x0 * s);
    __syncthreads();
    qp[j] = f2bf(o);
  }
}

// ---------------- Flash MFMA attention ----------------
__global__ __launch_bounds__(256, 2)
void attn_mfma(const ushort* __restrict__ q, const ushort* __restrict__ kv,
               const ushort* __restrict__ kpe, ushort* __restrict__ out) {
  const int qt = (int)gridDim.x - 1 - (int)blockIdx.x;
  const int bh = blockIdx.y;
  const int b = bh >> 4, h = bh & 15;
  const int tid = threadIdx.x;
  const int wave = tid >> 6, lane = tid & 63;
  const int lm = lane & 15, quad = lane >> 4;
  const int wq = wave * 32;
  const float scale = 0.07216878364870323f;

  __shared__ __align__(16) char smem[62464];
  ushort (*Ks)[200] = (ushort(*)[200])smem;
  ushort (*Vt)[72]  = (ushort(*)[72])(smem + 25600);
  ushort (*Pm)[72]  = (ushort(*)[72])(smem + 44032);
  ushort (*Qs)[200] = (ushort(*)[200])smem;

  const size_t tok0 = (size_t)b * 2048;
  const int q0 = qt * 128;

  {
    const ushort* qbase = q + (tok0 + q0) * 3072 + (size_t)h * 192;
#pragma unroll
    for (int it = 0; it < 12; ++it) {
      int idx = (it * 256 + tid) * 8;
      int row = idx / 192, col = idx % 192;
      *(uint4*)&Qs[row][col] = *(const uint4*)(qbase + (size_t)row * 3072 + col);
    }
  }
  __syncthreads();
  short8 qf[2][6];
#pragma unroll
  for (int mt = 0; mt < 2; ++mt)
#pragma unroll
    for (int kk = 0; kk < 6; ++kk)
      qf[mt][kk] = *(const short8*)&Qs[wq + mt * 16 + lm][kk * 32 + quad * 8];
  __syncthreads();

  f32x4 o[2][8];
  const f32x4 z4 = {0.f, 0.f, 0.f, 0.f};
#pragma unroll
  for (int mt = 0; mt < 2; ++mt)
#pragma unroll
    for (int nt = 0; nt < 8; ++nt) o[mt][nt] = z4;
  float m_run[8], l_run[8];
#pragma unroll
  for (int i = 0; i < 8; ++i) { m_run[i] = -3.0e38f; l_run[i] = 0.f; }

  const int nkt = 2 * qt + 2;
  for (int kt = 0; kt < nkt; ++kt) {
    const int kb = kt * 64;
    {
      const int krow = tid >> 2, kq = tid & 3;
      const ushort* src = kv + ((tok0 + kb + krow) * 16 + h) * 256 + kq * 32;
#pragma unroll
      for (int i = 0; i < 4; ++i)
        *(uint4*)&Ks[krow][kq * 32 + i * 8] = *(const uint4*)(src + i * 8);
      const ushort* psrc = kpe + (tok0 + kb + krow) * 64 + kq * 16;
      *(uint4*)&Ks[krow][128 + kq * 16]     = *(const uint4*)(psrc);
      *(uint4*)&Ks[krow][128 + kq * 16 + 8] = *(const uint4*)(psrc + 8);
      const int kgrp = (tid & 15) * 4, dgrp = (tid >> 4) * 8;
      uint4 vv[4];
#pragma unroll
      for (int i = 0; i < 4; ++i)
        vv[i] = *(const uint4*)(kv + ((tok0 + kb + kgrp + i) * 16 + h) * 256 + 128 + dgrp);
#pragma unroll
      for (int j = 0; j < 8; ++j) {
        short4v w;
#pragma unroll
        for (int i = 0; i < 4; ++i) w[i] = (short)((const ushort*)&vv[i])[j];
        *(short4v*)&Vt[dgrp + j][kgrp] = w;
      }
    }
    __syncthreads();

    f32x4 s_acc[2][4];
#pragma unroll
    for (int mt = 0; mt < 2; ++mt)
#pragma unroll
      for (int nt = 0; nt < 4; ++nt) s_acc[mt][nt] = z4;
#pragma unroll
    for (int kk = 0; kk < 6; ++kk) {
      short8 kf[4];
#pragma unroll
      for (int nt = 0; nt < 4; ++nt)
        kf[nt] = *(const short8*)&Ks[nt * 16 + lm][kk * 32 + quad * 8];
#pragma unroll
      for (int mt = 0; mt < 2; ++mt)
#pragma unroll
        for (int nt = 0; nt < 4; ++nt)
          s_acc[mt][nt] = __builtin_amdgcn_mfma_f32_16x16x32_bf16(
              qf[mt][kk], kf[nt], s_acc[mt][nt], 0, 0, 0);
    }

    // wave-uniform: interior tiles (all keys <= min q-row of this wave) skip mask
    const bool full = (kb + 63) <= (q0 + wq);
#pragma unroll
    for (int mt = 0; mt < 2; ++mt) {
#pragma unroll
      for (int r = 0; r < 4; ++r) {
        const int qg = q0 + wq + mt * 16 + quad * 4 + r;
        float sv[4];
        float rm = -3.0e38f;
        if (full) {
#pragma unroll
          for (int nt = 0; nt < 4; ++nt) {
            float s = s_acc[mt][nt][r] * scale;
            sv[nt] = s;
            rm = fmaxf(rm, s);
          }
        } else {
#pragma unroll
          for (int nt = 0; nt < 4; ++nt) {
            const int key = kb + nt * 16 + lm;
            float s = s_acc[mt][nt][r] * scale;
            s = (key <= qg) ? s : -3.0e38f;
            sv[nt] = s;
            rm = fmaxf(rm, s);
          }
        }
#pragma unroll
        for (int off = 1; off < 16; off <<= 1) rm = fmaxf(rm, __shfl_xor(rm, off));
        const int li = mt * 4 + r;
        const float mnew = fmaxf(m_run[li], rm);
        const float alpha = __expf(m_run[li] - mnew);
        m_run[li] = mnew;
        float rs = 0.f;
        ushort pb[4];
#pragma unroll
        for (int nt = 0; nt < 4; ++nt) {
          float p = __expf(sv[nt] - mnew);
          rs += p;
          pb[nt] = f2bf(p);
        }
#pragma unroll
        for (int off = 1; off < 16; off <<= 1) rs += __shfl_xor(rs, off);
        l_run[li] = l_run[li] * alpha + rs;
#pragma unroll
        for (int nt = 0; nt < 8; ++nt) o[mt][nt][r] *= alpha;
        const int qrow = wq + mt * 16 + quad * 4 + r;
#pragma unroll
        for (int nt = 0; nt < 4; ++nt) Pm[qrow][nt * 16 + lm] = pb[nt];
      }
    }

#pragma unroll
    for (int kt2 = 0; kt2 < 2; ++kt2) {
      short8 pa[2];
#pragma unroll
      for (int mt = 0; mt < 2; ++mt)
        pa[mt] = *(const short8*)&Pm[wq + mt * 16 + lm][kt2 * 32 + quad * 8];
#pragma unroll
      for (int nt = 0; nt < 8; ++nt) {
        short8 vb = *(const short8*)&Vt[nt * 16 + lm][kt2 * 32 + quad * 8];
#pragma unroll
        for (int mt = 0; mt < 2; ++mt)
          o[mt][nt] = __builtin_amdgcn_mfma_f32_16x16x32_bf16(
              pa[mt], vb, o[mt][nt], 0, 0, 0);
      }
    }
    __syncthreads();
  }

  ushort* obase = out + (tok0 + q0) * 2048 + h * 128;
#pragma unroll
  for (int mt = 0; mt < 2; ++mt) {
#pragma unroll
    for (int r = 0; r < 4; ++r) {
      const int qrow = wq + mt * 16 + quad * 4 + r;
      const float inv = 1.f / l_run[mt * 4 + r];
#pragma unroll
      for (int nt = 0; nt < 8; ++nt)
        obase[(size_t)qrow * 2048 + nt * 16 + lm] = f2bf(o[mt][nt][r] * inv);
    }
  }
}

extern "C" void kernel_launch(void* const* d_in, const int* in_sizes, int n_in,
                              void* d_out, int out_size, void* d_ws, size_t ws_size,
                              hipStream_t stream) {
  const float* hidden = (const float*)d_in[0];
  const int*   pos    = (const int*)d_in[1];
  const float* Wq     = (const float*)d_in[2];
  const float* Wkva   = (const float*)d_in[3];
  const float* w_kvln = (const float*)d_in[4];
  const float* Wkvb   = (const float*)d_in[5];
  const float* Wo     = (const float*)d_in[6];
  const float* Wg     = (const float*)d_in[7];
  const float* Wu     = (const float*)d_in[8];
  const float* Wd     = (const float*)d_in[9];
  const float* w_ln1  = (const float*)d_in[10];
  const float* w_ln2  = (const float*)d_in[11];
  float* out = (float*)d_out;

  char* ws = (char*)d_ws;
  ushort* xn    = (ushort*)(ws);
  char*   R1    = ws + 16777216;
  ushort* qb    = (ushort*)(R1);
  float*  ckv   = (float*)(R1 + 25165824);
  ushort* cn    = (ushort*)(R1 + 34603008);
  ushort* kvb   = (ushort*)(R1 + 38797312);
  ushort* kpe   = (ushort*)(R1 + 72351744);
  ushort* attno = (ushort*)(R1 + 72876032);
  ushort* gb    = (ushort*)(R1);                    // (T,10944) aliases R1
  float*  h1    = (float*)(ws + 196083712);

  char* WSL = ws + 106430464;                       // 89,653,248 B slot region
  ushort* wq_bf   = (ushort*)(WSL);                 // 3072 rows; wkva contiguous after
  ushort* wkva_bf = (ushort*)(WSL + 12582912);      // 576 rows -> combined N=3648
  ushort* wkvb_bf = (ushort*)(WSL + 14942208);
  ushort* wo_bf   = (ushort*)(WSL + 19136512);
  ushort* wg_bf   = (ushort*)(WSL);                 // phase B
  ushort* wu_bf   = (ushort*)(WSL + 44826624);
  ushort* wd_bf   = (ushort*)(WSL + 44826624);      // reuses wu slot after up GEMM

  cvt_bf16<<<3072, 256, 0, stream>>>(Wq,   wq_bf,   786432);
  cvt_bf16<<<576,  256, 0, stream>>>(Wkva, wkva_bf, 147456);
  cvt_bf16<<<1024, 256, 0, stream>>>(Wkvb, wkvb_bf, 262144);
  cvt_bf16<<<2048, 256, 0, stream>>>(Wo,   wo_bf,   524288);
  cvt_bf16<<<10944, 256, 0, stream>>>(Wu,  wu_bf,   2801664);

  rms_bf16<<<4096, 256, 0, stream>>>(hidden, 2048, 2048, 1.f / 2048.f, w_ln1, xn, 2048);
  // merged q + ckv projection (N = 3072 + 576 = 3648, weights contiguous)
  gemm_as<4><<<dim3(32, 29), 256, 0, stream>>>(xn, wq_bf, qb, ckv, 4096, 3648, 2048);
  rms_bf16<<<4096, 256, 0, stream>>>(ckv, 576, 512, 1.f / 512.f, w_kvln, cn, 512);
  gemm_as<0><<<dim3(32, 32), 256, 0, stream>>>(cn, wkvb_bf, kvb, nullptr, 4096, 4096, 512);
  rope_kernel<<<4096, 64, 0, stream>>>(qb, ckv, pos, kpe);
  attn_mfma<<<dim3(16, 32), 256, 0, stream>>>(qb, kvb, kpe, attno);
  gemm_as<2><<<dim3(32, 16), 256, 0, stream>>>(attno, wo_bf, h1, hidden, 4096, 2048, 2048);
  rms_bf16<<<4096, 256, 0, stream>>>(h1, 2048, 2048, 1.f / 2048.f, w_ln2, xn, 2048);

  cvt_bf16<<<10944, 256, 0, stream>>>(Wg, wg_bf, 2801664);
  gemm_as<0><<<dim3(32, 86), 256, 0, stream>>>(xn, wg_bf, gb, nullptr, 4096, 10944, 2048);
  gemm_as<3><<<dim3(32, 86), 256, 0, stream>>>(xn, wu_bf, gb, gb, 4096, 10944, 2048);
  cvt_bf16<<<10944, 256, 0, stream>>>(Wd, wd_bf, 2801664);
  gemm_as<2><<<dim3(32, 16), 256, 0, stream>>>(gb, wd_bf, out, h1, 4096, 2048, 10944);
}